// Round 1
// baseline (1638.950 us; speedup 1.0000x reference)
//
#include <hip/hip_runtime.h>
#include <stdint.h>

typedef __bf16 bf16;
typedef __attribute__((ext_vector_type(8))) __bf16 bf16x8;
typedef __attribute__((ext_vector_type(4))) float f32x4;

// async global->LDS, 16B per lane. LDS dest must be wave-uniform base + lane*16.
__device__ __forceinline__ void async_copy16(void* lds, const void* gp) {
    __builtin_amdgcn_global_load_lds(
        (__attribute__((address_space(1))) void*)(gp),
        (__attribute__((address_space(3))) void*)(lds), 16, 0, 0);
}

// LDS bank-conflict swizzle: logical chunk lq (16B) of row R lives at physical
// chunk (lq + (R>>1)) & 3.  Read-side address (in bf16 elements):
__device__ __forceinline__ const bf16* lread(const bf16* base, int R, int lq) {
    return base + R * 32 + (((lq + (R >> 1)) & 3) << 3);
}
// Write side: lane t stages LDS offset t*16B = row (t>>2), phys chunk (t&3);
// the logical chunk it must fetch is ((t&3) - (t>>3)) & 3.

// XCD-aware block remap: xcd = flat%8 owns a contiguous slab of row-panels and
// iterates all N-tiles within a panel, so an A row-panel is fetched by ONE XCD's L2.
__device__ __forceinline__ void xcd_remap(int& bx, int& by, int& bz) {
    int gx = gridDim.x, gy = gridDim.y, gz = gridDim.z;
    int panels = gy * gz;
    if (panels & 7) { bx = blockIdx.x; by = blockIdx.y; bz = blockIdx.z; return; }
    int L = (blockIdx.z * gy + blockIdx.y) * gx + blockIdx.x;
    int X = L & 7, S = L >> 3;
    bx = S % gx;
    int P = S / gx;
    int byT = X * (panels >> 3) + P;
    bz = byT / gy;
    by = byT % gy;
}

// ---------------- router ----------------

__global__ __launch_bounds__(256) void cnorm_kernel(const float* __restrict__ centers,
                                                    float* __restrict__ invc) {
    int e = blockIdx.x, t = threadIdx.x;
    float4 v = ((const float4*)(centers + (size_t)e * 1024))[t];
    float ss = v.x * v.x + v.y * v.y + v.z * v.z + v.w * v.w;
    #pragma unroll
    for (int o = 32; o; o >>= 1) ss += __shfl_down(ss, o);
    __shared__ float red[4];
    if ((t & 63) == 0) red[t >> 6] = ss;
    __syncthreads();
    if (t == 0) invc[e] = 1.f / fmaxf(sqrtf(red[0] + red[1] + red[2] + red[3]), 1e-12f);
}

__global__ __launch_bounds__(256) void router_convert_kernel(
    const float* __restrict__ X, const float* __restrict__ centers,
    const float* __restrict__ invc, bf16* __restrict__ hid, float* __restrict__ P) {
    int tok = blockIdx.x, t = threadIdx.x;
    int b = tok >> 10, s = tok & 1023;
    float4 v = ((const float4*)(X + (size_t)tok * 1024))[t];
    union { bf16 h[4]; uint2 u; } cv;
    cv.h[0] = (bf16)v.x; cv.h[1] = (bf16)v.y; cv.h[2] = (bf16)v.z; cv.h[3] = (bf16)v.w;
    ((uint2*)(hid + (size_t)tok * 1024))[t] = cv.u;
    float ss = v.x * v.x + v.y * v.y + v.z * v.z + v.w * v.w;
    float dots[8];
    #pragma unroll
    for (int e = 0; e < 8; e++) {
        float4 c = ((const float4*)(centers + (size_t)e * 1024))[t];
        dots[e] = v.x * c.x + v.y * c.y + v.z * c.z + v.w * c.w;
    }
    #pragma unroll
    for (int o = 32; o; o >>= 1) {
        ss += __shfl_down(ss, o);
        #pragma unroll
        for (int e = 0; e < 8; e++) dots[e] += __shfl_down(dots[e], o);
    }
    __shared__ float red[4][9];
    if ((t & 63) == 0) {
        red[t >> 6][0] = ss;
        #pragma unroll
        for (int e = 0; e < 8; e++) red[t >> 6][1 + e] = dots[e];
    }
    __syncthreads();
    if (t < 8) {
        float S = red[0][0] + red[1][0] + red[2][0] + red[3][0];
        float rinv = 1.f / fmaxf(sqrtf(S), 1e-12f);
        float d = red[0][1 + t] + red[1][1 + t] + red[2][1 + t] + red[3][1 + t];
        P[((size_t)(b * 8 + t) << 10) + s] = d * rinv * invc[t];
    }
}

__global__ __launch_bounds__(256) void softmax_kernel(float* __restrict__ P) {
    int row = blockIdx.x, t = threadIdx.x;
    float4* p4 = (float4*)(P + ((size_t)row << 10));
    float4 v = p4[t];
    float mx = fmaxf(fmaxf(v.x, v.y), fmaxf(v.z, v.w));
    #pragma unroll
    for (int o = 32; o; o >>= 1) mx = fmaxf(mx, __shfl_down(mx, o));
    __shared__ float red[8];
    if ((t & 63) == 0) red[t >> 6] = mx;
    __syncthreads();
    float M = fmaxf(fmaxf(red[0], red[1]), fmaxf(red[2], red[3]));
    float e0 = expf(v.x - M), e1 = expf(v.y - M), e2 = expf(v.z - M), e3 = expf(v.w - M);
    float s = e0 + e1 + e2 + e3;
    #pragma unroll
    for (int o = 32; o; o >>= 1) s += __shfl_down(s, o);
    if ((t & 63) == 0) red[4 + (t >> 6)] = s;
    __syncthreads();
    float inv = 1.f / (red[4] + red[5] + red[6] + red[7]);
    p4[t] = make_float4(e0 * inv, e1 * inv, e2 * inv, e3 * inv);
}

__global__ __launch_bounds__(256) void zero_cnt_kernel(int* __restrict__ cnt) {
    cnt[blockIdx.x * 256 + threadIdx.x] = 0;
}

__global__ __launch_bounds__(1024) void topk_kernel(const float* __restrict__ P,
                                                    int* __restrict__ row_map,
                                                    float* __restrict__ gsc,
                                                    int* __restrict__ cnt,
                                                    int* __restrict__ inv) {
    int row = blockIdx.x, t = threadIdx.x;
    __shared__ unsigned long long keys[1024];
    float v = P[((size_t)row << 10) + t];
    unsigned u = __float_as_uint(v);
    u = (u & 0x80000000u) ? ~u : (u | 0x80000000u);
    keys[t] = ((unsigned long long)u << 32) | (unsigned)(~t);
    __syncthreads();
    for (int k = 2; k <= 1024; k <<= 1) {
        for (int j = k >> 1; j > 0; j >>= 1) {
            int ixj = t ^ j;
            if (ixj > t) {
                bool up = ((t & k) == 0);
                unsigned long long a = keys[t], b = keys[ixj];
                if ((a > b) == up) { keys[t] = b; keys[ixj] = a; }
            }
            __syncthreads();
        }
    }
    if (t >= 768) {
        int slot = t - 768;
        int s = (int)(~(unsigned)keys[t]) & 1023;
        int b = row >> 3, e = row & 7;
        int m = e * 4096 + b * 256 + slot;
        int tok = b * 1024 + s;
        row_map[m] = tok;
        gsc[m] = P[((size_t)row << 10) + s];
        // inverse map: token -> list of expert-slot indices (<=8, one per expert)
        int pos = atomicAdd(cnt + tok, 1);
        inv[tok * 8 + pos] = m;
    }
}

// ---------------- weight transpose-convert ----------------

__global__ __launch_bounds__(256) void transpose_cvt(
    const float* __restrict__ srcA, bf16* __restrict__ dstA, int batchA,
    const float* __restrict__ srcB, bf16* __restrict__ dstB, int R, int C) {
    int z = blockIdx.z;
    const float* src; bf16* dst;
    if (z < batchA) { src = srcA + (size_t)z * R * C; dst = dstA + (size_t)z * R * C; }
    else            { src = srcB + (size_t)(z - batchA) * R * C; dst = dstB + (size_t)(z - batchA) * R * C; }
    __shared__ float tile[32][33];
    int tx = threadIdx.x & 31, ty = threadIdx.x >> 5;
    int c0 = blockIdx.x * 32, r0 = blockIdx.y * 32;
    #pragma unroll
    for (int p = 0; p < 4; p++) {
        int r = p * 8 + ty;
        tile[r][tx] = src[(size_t)(r0 + r) * C + c0 + tx];
    }
    __syncthreads();
    #pragma unroll
    for (int p = 0; p < 4; p++) {
        int cl = p * 8 + ty;
        dst[(size_t)(c0 + cl) * R + r0 + tx] = (bf16)tile[tx][cl];
    }
}

// ---------------- fused gate+up GEMM: H = silu(X Wg) * (X Wu) ----------------
// tile 128(M) x 64(N) each of g,u; K=1024. mode: 0=shared, 1=uncond, 2=routed

__global__ __launch_bounds__(256) void gateup_kernel(
    const bf16* __restrict__ X, const int* __restrict__ row_map,
    const bf16* __restrict__ WgT, const bf16* __restrict__ WuT,
    bf16* __restrict__ H, int Mz, int m_base, const int* __restrict__ labels, int mode) {
    int bx, by, z; xcd_remap(bx, by, z);
    if (mode == 1) { int b = (m_base + by * 128) >> 10; if (labels[b] != 1000) return; }
    if (mode == 2) { int b = (m_base + by * 128) >> 8;  if (labels[b] == 1000) return; }
    __shared__ bf16 lds[8192];       // As 128x32 | Bg 64x32 | Bu 64x32
    bf16* As = lds; bf16* Bg = lds + 4096; bf16* Bu = lds + 6144;
    const int t = threadIdx.x;
    const bf16* Wg_e = WgT + (size_t)z * 2048 * 1024;
    const bf16* Wu_e = WuT + (size_t)z * 2048 * 1024;
    bf16* H_e = H + (size_t)z * Mz * 2048;

    const int m0 = by * 128, n0 = bx * 64;
    const int r = t >> 2;
    const int ce = (((t & 3) - (t >> 3)) & 3) * 8;   // swizzled source chunk
    int tok0, tok1;
    if (mode == 2) {
        const int* rm = row_map + (size_t)z * Mz;
        tok0 = rm[m0 + r]; tok1 = rm[m0 + 64 + r];
    } else { tok0 = m_base + m0 + r; tok1 = m_base + m0 + 64 + r; }
    const bf16* pa0 = X + (size_t)tok0 * 1024 + ce;
    const bf16* pa1 = X + (size_t)tok1 * 1024 + ce;
    const bf16* pg  = Wg_e + (size_t)(n0 + r) * 1024 + ce;
    const bf16* pu  = Wu_e + (size_t)(n0 + r) * 1024 + ce;
    bf16* lA0 = As + t * 8; bf16* lA1 = As + 2048 + t * 8;
    bf16* lBg = Bg + t * 8; bf16* lBu = Bu + t * 8;

    const int l = t & 63, w = t >> 6;
    const int wm = w >> 1, wn = w & 1;
    const int lr = l & 15, lq = l >> 4;

    f32x4 accg[4][2] = {}, accu[4][2] = {};
    for (int kt = 0; kt < 1024; kt += 32) {
        __syncthreads();
        async_copy16(lA0, pa0); async_copy16(lA1, pa1);
        async_copy16(lBg, pg);  async_copy16(lBu, pu);
        pa0 += 32; pa1 += 32; pg += 32; pu += 32;
        __syncthreads();
        bf16x8 a[4], bg[2], bu[2];
        #pragma unroll
        for (int mi = 0; mi < 4; mi++)
            a[mi] = *(const bf16x8*)lread(As, wm * 64 + mi * 16 + lr, lq);
        #pragma unroll
        for (int ni = 0; ni < 2; ni++) {
            bg[ni] = *(const bf16x8*)lread(Bg, wn * 32 + ni * 16 + lr, lq);
            bu[ni] = *(const bf16x8*)lread(Bu, wn * 32 + ni * 16 + lr, lq);
        }
        #pragma unroll
        for (int mi = 0; mi < 4; mi++)
            #pragma unroll
            for (int ni = 0; ni < 2; ni++) {
                accg[mi][ni] = __builtin_amdgcn_mfma_f32_16x16x32_bf16(a[mi], bg[ni], accg[mi][ni], 0, 0, 0);
                accu[mi][ni] = __builtin_amdgcn_mfma_f32_16x16x32_bf16(a[mi], bu[ni], accu[mi][ni], 0, 0, 0);
            }
    }
    #pragma unroll
    for (int mi = 0; mi < 4; mi++)
        #pragma unroll
        for (int ni = 0; ni < 2; ni++)
            #pragma unroll
            for (int rr = 0; rr < 4; rr++) {
                int m = m0 + wm * 64 + mi * 16 + lq * 4 + rr;
                int n = n0 + wn * 32 + ni * 16 + lr;
                float g = accg[mi][ni][rr], uu = accu[mi][ni][rr];
                float h = g / (1.f + __expf(-g)) * uu;
                H_e[(size_t)m * 2048 + n] = (bf16)h;
            }
}

// ---------------- down GEMM: out = H WdT^T, K=2048, N=1024 ----------------
// mode: 0=shared (plain =), 1=uncond (+=), 2=routed -> scaled plain store to stage,
// 3=routed legacy atomic scatter (fallback when workspace too small for stage)

__global__ __launch_bounds__(256) void down_kernel(
    const bf16* __restrict__ Hbase, const bf16* __restrict__ WdT,
    float* __restrict__ out, float* __restrict__ stage, int Mz, int m_base,
    const int* __restrict__ row_map, const float* __restrict__ gsc,
    const int* __restrict__ labels, int mode) {
    int bx, by, z; xcd_remap(bx, by, z);
    if (mode == 1) { int b = (m_base + by * 128) >> 10; if (labels[b] != 1000) return; }
    if (mode >= 2) { int b = (m_base + by * 128) >> 8;  if (labels[b] == 1000) return; }
    __shared__ bf16 lds[8192];  // As 128x32 | Bs 128x32
    bf16* As = lds; bf16* Bs = lds + 4096;
    const int t = threadIdx.x;
    const bf16* A_e = Hbase + (size_t)z * Mz * 2048;
    const bf16* B_e = WdT + (size_t)z * 1024 * 2048;
    const int m0 = by * 128, n0 = bx * 128;
    const int r = t >> 2;
    const int ce = (((t & 3) - (t >> 3)) & 3) * 8;   // swizzled source chunk
    const bf16* pa0 = A_e + (size_t)(m0 + r) * 2048 + ce;
    const bf16* pa1 = A_e + (size_t)(m0 + 64 + r) * 2048 + ce;
    const bf16* pb0 = B_e + (size_t)(n0 + r) * 2048 + ce;
    const bf16* pb1 = B_e + (size_t)(n0 + 64 + r) * 2048 + ce;
    bf16* lA0 = As + t * 8; bf16* lA1 = As + 2048 + t * 8;
    bf16* lB0 = Bs + t * 8; bf16* lB1 = Bs + 2048 + t * 8;

    const int l = t & 63, w = t >> 6;
    const int wm = w >> 1, wn = w & 1;
    const int lr = l & 15, lq = l >> 4;

    f32x4 acc[4][4] = {};
    for (int kt = 0; kt < 2048; kt += 32) {
        __syncthreads();
        async_copy16(lA0, pa0); async_copy16(lA1, pa1);
        async_copy16(lB0, pb0); async_copy16(lB1, pb1);
        pa0 += 32; pa1 += 32; pb0 += 32; pb1 += 32;
        __syncthreads();
        bf16x8 a[4], bb[4];
        #pragma unroll
        for (int mi = 0; mi < 4; mi++)
            a[mi] = *(const bf16x8*)lread(As, wm * 64 + mi * 16 + lr, lq);
        #pragma unroll
        for (int ni = 0; ni < 4; ni++)
            bb[ni] = *(const bf16x8*)lread(Bs, wn * 64 + ni * 16 + lr, lq);
        #pragma unroll
        for (int mi = 0; mi < 4; mi++)
            #pragma unroll
            for (int ni = 0; ni < 4; ni++)
                acc[mi][ni] = __builtin_amdgcn_mfma_f32_16x16x32_bf16(a[mi], bb[ni], acc[mi][ni], 0, 0, 0);
    }
    #pragma unroll
    for (int mi = 0; mi < 4; mi++)
        #pragma unroll
        for (int ni = 0; ni < 4; ni++)
            #pragma unroll
            for (int rr = 0; rr < 4; rr++) {
                int m = m0 + wm * 64 + mi * 16 + lq * 4 + rr;
                int n = n0 + wn * 64 + ni * 16 + lr;
                float v = acc[mi][ni][rr];
                if (mode == 0) {
                    out[(size_t)(m_base + m) * 1024 + n] = v;
                } else if (mode == 1) {
                    out[(size_t)(m_base + m) * 1024 + n] += v;
                } else if (mode == 2) {
                    size_t em = (size_t)z * Mz + m;
                    stage[em * 1024 + n] = v * gsc[em];
                } else {
                    size_t em = (size_t)z * Mz + m;
                    int tok = row_map[em];
                    atomicAdd(out + (size_t)tok * 1024 + n, v * gsc[em]);
                }
            }
}

// ---------------- combine: out[tok] += sum over experts that picked tok ----------------
// stage rows are already gsc-scaled; inverse map has <=8 entries per token.

__global__ __launch_bounds__(256) void combine_kernel(
    const float* __restrict__ stage, const int* __restrict__ cnt,
    const int* __restrict__ inv, const int* __restrict__ labels,
    float* __restrict__ out) {
    int tok = blockIdx.x;
    if (labels[tok >> 10] == 1000) return;   // routed output discarded for uncond batches
    int c = cnt[tok];
    if (c == 0) return;
    int t = threadIdx.x;
    float4* o4 = (float4*)(out + (size_t)tok * 1024);
    float4 acc = o4[t];
    for (int i = 0; i < c; i++) {
        int m = inv[tok * 8 + i];
        float4 v = ((const float4*)(stage + (size_t)m * 1024))[t];
        acc.x += v.x; acc.y += v.y; acc.z += v.z; acc.w += v.w;
    }
    o4[t] = acc;
}

// ---------------- host ----------------

extern "C" void kernel_launch(void* const* d_in, const int* in_sizes, int n_in,
                              void* d_out, int out_size, void* d_ws, size_t ws_size,
                              hipStream_t stream) {
    (void)in_sizes; (void)n_in; (void)out_size;
    const float* X       = (const float*)d_in[0];
    const int*   labels  = (const int*)d_in[1];
    const float* centers = (const float*)d_in[2];
    const float* Wg  = (const float*)d_in[3];
    const float* Wu  = (const float*)d_in[4];
    const float* Wd  = (const float*)d_in[5];
    const float* uWg = (const float*)d_in[6];
    const float* uWu = (const float*)d_in[7];
    const float* uWd = (const float*)d_in[8];
    const float* sWg = (const float*)d_in[9];
    const float* sWu = (const float*)d_in[10];
    const float* sWd = (const float*)d_in[11];
    float* out = (float*)d_out;

    char* w = (char*)d_ws;
    auto alloc = [&](size_t n) { char* p = w; w += (n + 255) & ~(size_t)255; return p; };
    bf16* hid  = (bf16*)alloc((size_t)16384 * 1024 * 2);
    bf16* WgT  = (bf16*)alloc((size_t)8 * 2048 * 1024 * 2);
    bf16* WuT  = (bf16*)alloc((size_t)8 * 2048 * 1024 * 2);
    bf16* WdT  = (bf16*)alloc((size_t)8 * 2048 * 1024 * 2);
    bf16* uWgT = (bf16*)alloc((size_t)2048 * 1024 * 2);
    bf16* uWuT = (bf16*)alloc((size_t)2048 * 1024 * 2);
    bf16* uWdT = (bf16*)alloc((size_t)2048 * 1024 * 2);
    bf16* sWgT = (bf16*)alloc((size_t)2048 * 1024 * 2);
    bf16* sWuT = (bf16*)alloc((size_t)2048 * 1024 * 2);
    bf16* sWdT = (bf16*)alloc((size_t)2048 * 1024 * 2);
    float* P     = (float*)alloc((size_t)128 * 1024 * 4);
    float* invc  = (float*)alloc(256);
    int*   rmap  = (int*)alloc((size_t)32768 * 4);
    float* gsc   = (float*)alloc((size_t)32768 * 4);
    int*   cnt   = (int*)alloc((size_t)16384 * 4);
    int*   inv   = (int*)alloc((size_t)16384 * 8 * 4);

    // routed-output staging buffer (gsc-scaled rows, plain stores; no atomics)
    size_t used0 = (size_t)(w - (char*)d_ws);
    size_t rem0  = ws_size > used0 ? ws_size - used0 : 0;
    const size_t STAGE_BYTES = (size_t)32768 * 1024 * 4;   // 128 MiB
    const size_t HMIN_BYTES  = (size_t)4096 * 2048 * 2;    // H for EPG=1
    float* stage = nullptr;
    if (rem0 >= STAGE_BYTES + HMIN_BYTES + 4096)
        stage = (float*)alloc(STAGE_BYTES);

    size_t used = (size_t)(w - (char*)d_ws);
    size_t hcap = ws_size > used ? ws_size - used : 0;
    bf16* H = (bf16*)w;
    long maxRows = (long)(hcap / ((size_t)2048 * 2));
    int CR = (int)(maxRows < 16384 ? maxRows : 16384);
    CR &= ~127;
    if (CR < 128) CR = 128;
    int EPG = 0;
    if (maxRows >= 32768) EPG = 8;
    else if (maxRows >= 16384) EPG = 4;
    else if (maxRows >= 8192)  EPG = 2;
    else if (maxRows >= 4096)  EPG = 1;

    const size_t WSTRIDE = (size_t)2048 * 1024;
    const int rmode = stage ? 2 : 3;

    cnorm_kernel<<<8, 256, 0, stream>>>(centers, invc);
    router_convert_kernel<<<16384, 256, 0, stream>>>(X, centers, invc, hid, P);
    softmax_kernel<<<128, 256, 0, stream>>>(P);
    zero_cnt_kernel<<<64, 256, 0, stream>>>(cnt);
    topk_kernel<<<128, 1024, 0, stream>>>(P, rmap, gsc, cnt, inv);
    transpose_cvt<<<dim3(64, 32, 16), 256, 0, stream>>>(Wg, WgT, 8, Wu, WuT, 1024, 2048);
    transpose_cvt<<<dim3(32, 64, 8), 256, 0, stream>>>(Wd, WdT, 8, nullptr, nullptr, 2048, 1024);
    transpose_cvt<<<dim3(64, 32, 2), 256, 0, stream>>>(uWg, uWgT, 1, sWg, sWgT, 1024, 2048);
    transpose_cvt<<<dim3(64, 32, 2), 256, 0, stream>>>(uWu, uWuT, 1, sWu, sWuT, 1024, 2048);
    transpose_cvt<<<dim3(32, 64, 2), 256, 0, stream>>>(uWd, uWdT, 1, sWd, sWdT, 2048, 1024);

    for (int m0 = 0; m0 < 16384; m0 += CR) {
        int rows = (16384 - m0 < CR) ? 16384 - m0 : CR;
        gateup_kernel<<<dim3(32, rows / 128, 1), 256, 0, stream>>>(
            hid, nullptr, sWgT, sWuT, H, rows, m0, labels, 0);
        down_kernel<<<dim3(8, rows / 128, 1), 256, 0, stream>>>(
            H, sWdT, out, nullptr, rows, m0, nullptr, nullptr, labels, 0);
    }
    for (int m0 = 0; m0 < 16384; m0 += CR) {
        int rows = (16384 - m0 < CR) ? 16384 - m0 : CR;
        gateup_kernel<<<dim3(32, rows / 128, 1), 256, 0, stream>>>(
            hid, nullptr, uWgT, uWuT, H, rows, m0, labels, 1);
        down_kernel<<<dim3(8, rows / 128, 1), 256, 0, stream>>>(
            H, uWdT, out, nullptr, rows, m0, nullptr, nullptr, labels, 1);
    }
    if (EPG > 0) {
        for (int g = 0; g < 8; g += EPG) {
            gateup_kernel<<<dim3(32, 32, EPG), 256, 0, stream>>>(
                hid, rmap + (size_t)g * 4096, WgT + (size_t)g * WSTRIDE,
                WuT + (size_t)g * WSTRIDE, H, 4096, 0, labels, 2);
            down_kernel<<<dim3(8, 32, EPG), 256, 0, stream>>>(
                H, WdT + (size_t)g * WSTRIDE, out,
                stage ? stage + (size_t)g * 4096 * 1024 : nullptr, 4096, 0,
                rmap + (size_t)g * 4096, gsc + (size_t)g * 4096, labels, rmode);
        }
    } else {
        for (int e = 0; e < 8; e++) {
            for (int m0 = 0; m0 < 4096; m0 += CR) {
                int rows = (4096 - m0 < CR) ? 4096 - m0 : CR;
                gateup_kernel<<<dim3(32, rows / 128, 1), 256, 0, stream>>>(
                    hid, rmap + (size_t)e * 4096 + m0, WgT + (size_t)e * WSTRIDE,
                    WuT + (size_t)e * WSTRIDE, H, rows, m0, labels, 2);
                down_kernel<<<dim3(8, rows / 128, 1), 256, 0, stream>>>(
                    H, WdT + (size_t)e * WSTRIDE, out,
                    stage ? stage + ((size_t)e * 4096 + m0) * 1024 : nullptr, rows, m0,
                    rmap + (size_t)e * 4096 + m0, gsc + (size_t)e * 4096 + m0, labels, rmode);
            }
        }
    }
    if (stage)
        combine_kernel<<<16384, 256, 0, stream>>>(stage, cnt, inv, labels, out);
}

// Round 2
// 1247.185 us; speedup vs baseline: 1.3141x; 1.3141x over previous
//
#include <hip/hip_runtime.h>
#include <stdint.h>

typedef __bf16 bf16;
typedef __attribute__((ext_vector_type(8))) __bf16 bf16x8;
typedef __attribute__((ext_vector_type(4))) float f32x4;

// async global->LDS, 16B per lane. LDS dest must be wave-uniform base + lane*16.
__device__ __forceinline__ void async_copy16(void* lds, const void* gp) {
    __builtin_amdgcn_global_load_lds(
        (__attribute__((address_space(1))) void*)(gp),
        (__attribute__((address_space(3))) void*)(lds), 16, 0, 0);
}

// LDS bank-conflict swizzle: logical chunk lq (16B) of row R lives at physical
// chunk (lq + (R>>1)) & 3.  Read-side address (in bf16 elements):
__device__ __forceinline__ const bf16* lread(const bf16* base, int R, int lq) {
    return base + R * 32 + (((lq + (R >> 1)) & 3) << 3);
}
// Write side: lane t stages LDS offset t*16B = row (t>>2), phys chunk (t&3);
// the logical chunk it must fetch is ((t&3) - (t>>3)) & 3.

// XCD-aware block remap: xcd = flat%8 owns a contiguous slab of row-panels and
// iterates all N-tiles within a panel, so an A row-panel is fetched by ONE XCD's L2.
__device__ __forceinline__ void xcd_remap(int& bx, int& by, int& bz) {
    int gx = gridDim.x, gy = gridDim.y, gz = gridDim.z;
    int panels = gy * gz;
    if (panels & 7) { bx = blockIdx.x; by = blockIdx.y; bz = blockIdx.z; return; }
    int L = (blockIdx.z * gy + blockIdx.y) * gx + blockIdx.x;
    int X = L & 7, S = L >> 3;
    bx = S % gx;
    int P = S / gx;
    int byT = X * (panels >> 3) + P;
    bz = byT / gy;
    by = byT % gy;
}

// ---------------- router ----------------

__global__ __launch_bounds__(256) void cnorm_kernel(const float* __restrict__ centers,
                                                    float* __restrict__ invc) {
    int e = blockIdx.x, t = threadIdx.x;
    float4 v = ((const float4*)(centers + (size_t)e * 1024))[t];
    float ss = v.x * v.x + v.y * v.y + v.z * v.z + v.w * v.w;
    #pragma unroll
    for (int o = 32; o; o >>= 1) ss += __shfl_down(ss, o);
    __shared__ float red[4];
    if ((t & 63) == 0) red[t >> 6] = ss;
    __syncthreads();
    if (t == 0) invc[e] = 1.f / fmaxf(sqrtf(red[0] + red[1] + red[2] + red[3]), 1e-12f);
}

__global__ __launch_bounds__(256) void router_convert_kernel(
    const float* __restrict__ X, const float* __restrict__ centers,
    const float* __restrict__ invc, bf16* __restrict__ hid, float* __restrict__ P) {
    int tok = blockIdx.x, t = threadIdx.x;
    int b = tok >> 10, s = tok & 1023;
    float4 v = ((const float4*)(X + (size_t)tok * 1024))[t];
    union { bf16 h[4]; uint2 u; } cv;
    cv.h[0] = (bf16)v.x; cv.h[1] = (bf16)v.y; cv.h[2] = (bf16)v.z; cv.h[3] = (bf16)v.w;
    ((uint2*)(hid + (size_t)tok * 1024))[t] = cv.u;
    float ss = v.x * v.x + v.y * v.y + v.z * v.z + v.w * v.w;
    float dots[8];
    #pragma unroll
    for (int e = 0; e < 8; e++) {
        float4 c = ((const float4*)(centers + (size_t)e * 1024))[t];
        dots[e] = v.x * c.x + v.y * c.y + v.z * c.z + v.w * c.w;
    }
    #pragma unroll
    for (int o = 32; o; o >>= 1) {
        ss += __shfl_down(ss, o);
        #pragma unroll
        for (int e = 0; e < 8; e++) dots[e] += __shfl_down(dots[e], o);
    }
    __shared__ float red[4][9];
    if ((t & 63) == 0) {
        red[t >> 6][0] = ss;
        #pragma unroll
        for (int e = 0; e < 8; e++) red[t >> 6][1 + e] = dots[e];
    }
    __syncthreads();
    if (t < 8) {
        float S = red[0][0] + red[1][0] + red[2][0] + red[3][0];
        float rinv = 1.f / fmaxf(sqrtf(S), 1e-12f);
        float d = red[0][1 + t] + red[1][1 + t] + red[2][1 + t] + red[3][1 + t];
        P[((size_t)(b * 8 + t) << 10) + s] = d * rinv * invc[t];
    }
}

__global__ __launch_bounds__(256) void softmax_kernel(float* __restrict__ P) {
    int row = blockIdx.x, t = threadIdx.x;
    float4* p4 = (float4*)(P + ((size_t)row << 10));
    float4 v = p4[t];
    float mx = fmaxf(fmaxf(v.x, v.y), fmaxf(v.z, v.w));
    #pragma unroll
    for (int o = 32; o; o >>= 1) mx = fmaxf(mx, __shfl_down(mx, o));
    __shared__ float red[8];
    if ((t & 63) == 0) red[t >> 6] = mx;
    __syncthreads();
    float M = fmaxf(fmaxf(red[0], red[1]), fmaxf(red[2], red[3]));
    float e0 = expf(v.x - M), e1 = expf(v.y - M), e2 = expf(v.z - M), e3 = expf(v.w - M);
    float s = e0 + e1 + e2 + e3;
    #pragma unroll
    for (int o = 32; o; o >>= 1) s += __shfl_down(s, o);
    if ((t & 63) == 0) red[4 + (t >> 6)] = s;
    __syncthreads();
    float inv = 1.f / (red[4] + red[5] + red[6] + red[7]);
    p4[t] = make_float4(e0 * inv, e1 * inv, e2 * inv, e3 * inv);
}

__global__ __launch_bounds__(256) void zero_cnt_kernel(int* __restrict__ cnt) {
    cnt[blockIdx.x * 256 + threadIdx.x] = 0;
}

__global__ __launch_bounds__(1024) void topk_kernel(const float* __restrict__ P,
                                                    int* __restrict__ row_map,
                                                    float* __restrict__ gsc,
                                                    int* __restrict__ cnt,
                                                    int* __restrict__ inv) {
    int row = blockIdx.x, t = threadIdx.x;
    __shared__ unsigned long long keys[1024];
    float v = P[((size_t)row << 10) + t];
    unsigned u = __float_as_uint(v);
    u = (u & 0x80000000u) ? ~u : (u | 0x80000000u);
    keys[t] = ((unsigned long long)u << 32) | (unsigned)(~t);
    __syncthreads();
    for (int k = 2; k <= 1024; k <<= 1) {
        for (int j = k >> 1; j > 0; j >>= 1) {
            int ixj = t ^ j;
            if (ixj > t) {
                bool up = ((t & k) == 0);
                unsigned long long a = keys[t], b = keys[ixj];
                if ((a > b) == up) { keys[t] = b; keys[ixj] = a; }
            }
            __syncthreads();
        }
    }
    if (t >= 768) {
        int slot = t - 768;
        int s = (int)(~(unsigned)keys[t]) & 1023;
        int b = row >> 3, e = row & 7;
        int m = e * 4096 + b * 256 + slot;
        int tok = b * 1024 + s;
        row_map[m] = tok;
        gsc[m] = P[((size_t)row << 10) + s];
        // inverse map: token -> list of expert-slot indices (<=8, one per expert)
        int pos = atomicAdd(cnt + tok, 1);
        inv[tok * 8 + pos] = m;
    }
}

// ---------------- weight transpose-convert ----------------

__global__ __launch_bounds__(256) void transpose_cvt(
    const float* __restrict__ srcA, bf16* __restrict__ dstA, int batchA,
    const float* __restrict__ srcB, bf16* __restrict__ dstB, int R, int C) {
    int z = blockIdx.z;
    const float* src; bf16* dst;
    if (z < batchA) { src = srcA + (size_t)z * R * C; dst = dstA + (size_t)z * R * C; }
    else            { src = srcB + (size_t)(z - batchA) * R * C; dst = dstB + (size_t)(z - batchA) * R * C; }
    __shared__ float tile[32][33];
    int tx = threadIdx.x & 31, ty = threadIdx.x >> 5;
    int c0 = blockIdx.x * 32, r0 = blockIdx.y * 32;
    #pragma unroll
    for (int p = 0; p < 4; p++) {
        int r = p * 8 + ty;
        tile[r][tx] = src[(size_t)(r0 + r) * C + c0 + tx];
    }
    __syncthreads();
    #pragma unroll
    for (int p = 0; p < 4; p++) {
        int cl = p * 8 + ty;
        dst[(size_t)(c0 + cl) * R + r0 + tx] = (bf16)tile[tx][cl];
    }
}

// ---------------- fused gate+up GEMM: H = silu(X Wg) * (X Wu) ----------------
// tile 128(M) x 64(N) each of g,u; K=1024. mode: 0=shared, 1=uncond, 2=routed

__global__ __launch_bounds__(256) void gateup_kernel(
    const bf16* __restrict__ X, const int* __restrict__ row_map,
    const bf16* __restrict__ WgT, const bf16* __restrict__ WuT,
    bf16* __restrict__ H, int Mz, int m_base, const int* __restrict__ labels, int mode) {
    int bx, by, z; xcd_remap(bx, by, z);
    if (mode == 1) { int b = (m_base + by * 128) >> 10; if (labels[b] != 1000) return; }
    if (mode == 2) { int b = (m_base + by * 128) >> 8;  if (labels[b] == 1000) return; }
    __shared__ bf16 lds[8192];       // As 128x32 | Bg 64x32 | Bu 64x32
    bf16* As = lds; bf16* Bg = lds + 4096; bf16* Bu = lds + 6144;
    const int t = threadIdx.x;
    const bf16* Wg_e = WgT + (size_t)z * 2048 * 1024;
    const bf16* Wu_e = WuT + (size_t)z * 2048 * 1024;
    bf16* H_e = H + (size_t)z * Mz * 2048;

    const int m0 = by * 128, n0 = bx * 64;
    const int r = t >> 2;
    const int ce = (((t & 3) - (t >> 3)) & 3) * 8;   // swizzled source chunk
    int tok0, tok1;
    if (mode == 2) {
        const int* rm = row_map + (size_t)z * Mz;
        tok0 = rm[m0 + r]; tok1 = rm[m0 + 64 + r];
    } else { tok0 = m_base + m0 + r; tok1 = m_base + m0 + 64 + r; }
    const bf16* pa0 = X + (size_t)tok0 * 1024 + ce;
    const bf16* pa1 = X + (size_t)tok1 * 1024 + ce;
    const bf16* pg  = Wg_e + (size_t)(n0 + r) * 1024 + ce;
    const bf16* pu  = Wu_e + (size_t)(n0 + r) * 1024 + ce;
    bf16* lA0 = As + t * 8; bf16* lA1 = As + 2048 + t * 8;
    bf16* lBg = Bg + t * 8; bf16* lBu = Bu + t * 8;

    const int l = t & 63, w = t >> 6;
    const int wm = w >> 1, wn = w & 1;
    const int lr = l & 15, lq = l >> 4;

    f32x4 accg[4][2] = {}, accu[4][2] = {};
    for (int kt = 0; kt < 1024; kt += 32) {
        __syncthreads();
        async_copy16(lA0, pa0); async_copy16(lA1, pa1);
        async_copy16(lBg, pg);  async_copy16(lBu, pu);
        pa0 += 32; pa1 += 32; pg += 32; pu += 32;
        __syncthreads();
        bf16x8 a[4], bg[2], bu[2];
        #pragma unroll
        for (int mi = 0; mi < 4; mi++)
            a[mi] = *(const bf16x8*)lread(As, wm * 64 + mi * 16 + lr, lq);
        #pragma unroll
        for (int ni = 0; ni < 2; ni++) {
            bg[ni] = *(const bf16x8*)lread(Bg, wn * 32 + ni * 16 + lr, lq);
            bu[ni] = *(const bf16x8*)lread(Bu, wn * 32 + ni * 16 + lr, lq);
        }
        #pragma unroll
        for (int mi = 0; mi < 4; mi++)
            #pragma unroll
            for (int ni = 0; ni < 2; ni++) {
                accg[mi][ni] = __builtin_amdgcn_mfma_f32_16x16x32_bf16(a[mi], bg[ni], accg[mi][ni], 0, 0, 0);
                accu[mi][ni] = __builtin_amdgcn_mfma_f32_16x16x32_bf16(a[mi], bu[ni], accu[mi][ni], 0, 0, 0);
            }
    }
    #pragma unroll
    for (int mi = 0; mi < 4; mi++)
        #pragma unroll
        for (int ni = 0; ni < 2; ni++)
            #pragma unroll
            for (int rr = 0; rr < 4; rr++) {
                int m = m0 + wm * 64 + mi * 16 + lq * 4 + rr;
                int n = n0 + wn * 32 + ni * 16 + lr;
                float g = accg[mi][ni][rr], uu = accu[mi][ni][rr];
                float h = g / (1.f + __expf(-g)) * uu;
                H_e[(size_t)m * 2048 + n] = (bf16)h;
            }
}

// ---------------- down GEMM: out = H WdT^T, K=2048, N=1024 ----------------
// mode: 0=shared (plain =), 1=uncond (+=), 2=routed -> scaled bf16 store to stage,
// 3=routed legacy atomic scatter (fallback when workspace too small for stage)

__global__ __launch_bounds__(256) void down_kernel(
    const bf16* __restrict__ Hbase, const bf16* __restrict__ WdT,
    float* __restrict__ out, bf16* __restrict__ stage, int Mz, int m_base,
    const int* __restrict__ row_map, const float* __restrict__ gsc,
    const int* __restrict__ labels, int mode) {
    int bx, by, z; xcd_remap(bx, by, z);
    if (mode == 1) { int b = (m_base + by * 128) >> 10; if (labels[b] != 1000) return; }
    if (mode >= 2) { int b = (m_base + by * 128) >> 8;  if (labels[b] == 1000) return; }
    __shared__ bf16 lds[8192];  // As 128x32 | Bs 128x32
    bf16* As = lds; bf16* Bs = lds + 4096;
    const int t = threadIdx.x;
    const bf16* A_e = Hbase + (size_t)z * Mz * 2048;
    const bf16* B_e = WdT + (size_t)z * 1024 * 2048;
    const int m0 = by * 128, n0 = bx * 128;
    const int r = t >> 2;
    const int ce = (((t & 3) - (t >> 3)) & 3) * 8;   // swizzled source chunk
    const bf16* pa0 = A_e + (size_t)(m0 + r) * 2048 + ce;
    const bf16* pa1 = A_e + (size_t)(m0 + 64 + r) * 2048 + ce;
    const bf16* pb0 = B_e + (size_t)(n0 + r) * 2048 + ce;
    const bf16* pb1 = B_e + (size_t)(n0 + 64 + r) * 2048 + ce;
    bf16* lA0 = As + t * 8; bf16* lA1 = As + 2048 + t * 8;
    bf16* lB0 = Bs + t * 8; bf16* lB1 = Bs + 2048 + t * 8;

    const int l = t & 63, w = t >> 6;
    const int wm = w >> 1, wn = w & 1;
    const int lr = l & 15, lq = l >> 4;

    f32x4 acc[4][4] = {};
    for (int kt = 0; kt < 2048; kt += 32) {
        __syncthreads();
        async_copy16(lA0, pa0); async_copy16(lA1, pa1);
        async_copy16(lB0, pb0); async_copy16(lB1, pb1);
        pa0 += 32; pa1 += 32; pb0 += 32; pb1 += 32;
        __syncthreads();
        bf16x8 a[4], bb[4];
        #pragma unroll
        for (int mi = 0; mi < 4; mi++)
            a[mi] = *(const bf16x8*)lread(As, wm * 64 + mi * 16 + lr, lq);
        #pragma unroll
        for (int ni = 0; ni < 4; ni++)
            bb[ni] = *(const bf16x8*)lread(Bs, wn * 64 + ni * 16 + lr, lq);
        #pragma unroll
        for (int mi = 0; mi < 4; mi++)
            #pragma unroll
            for (int ni = 0; ni < 4; ni++)
                acc[mi][ni] = __builtin_amdgcn_mfma_f32_16x16x32_bf16(a[mi], bb[ni], acc[mi][ni], 0, 0, 0);
    }
    float gs[4][4];
    if (mode >= 2) {
        #pragma unroll
        for (int mi = 0; mi < 4; mi++)
            #pragma unroll
            for (int rr = 0; rr < 4; rr++)
                gs[mi][rr] = gsc[(size_t)z * Mz + m0 + wm * 64 + mi * 16 + lq * 4 + rr];
    }
    #pragma unroll
    for (int mi = 0; mi < 4; mi++)
        #pragma unroll
        for (int ni = 0; ni < 4; ni++)
            #pragma unroll
            for (int rr = 0; rr < 4; rr++) {
                int m = m0 + wm * 64 + mi * 16 + lq * 4 + rr;
                int n = n0 + wn * 64 + ni * 16 + lr;
                float v = acc[mi][ni][rr];
                if (mode == 0) {
                    out[(size_t)(m_base + m) * 1024 + n] = v;
                } else if (mode == 1) {
                    out[(size_t)(m_base + m) * 1024 + n] += v;
                } else if (mode == 2) {
                    size_t em = (size_t)z * Mz + m;
                    stage[em * 1024 + n] = (bf16)(v * gs[mi][rr]);
                } else {
                    size_t em = (size_t)z * Mz + m;
                    int tok = row_map[em];
                    atomicAdd(out + (size_t)tok * 1024 + n, v * gs[mi][rr]);
                }
            }
}

// ---------------- combine: out[tok] += sum over experts that picked tok ----------------
// stage rows are already gsc-scaled (bf16); inverse map has <=8 entries per token.

__global__ __launch_bounds__(256) void combine_kernel(
    const bf16* __restrict__ stage, const int* __restrict__ cnt,
    const int* __restrict__ inv, const int* __restrict__ labels,
    float* __restrict__ out) {
    int tok = blockIdx.x;
    if (labels[tok >> 10] == 1000) return;   // routed output discarded for uncond batches
    int c = cnt[tok];
    if (c == 0) return;
    int t = threadIdx.x;
    float4* o4 = (float4*)(out + (size_t)tok * 1024);
    float4 acc = o4[t];
    for (int i = 0; i < c; i++) {
        int m = inv[tok * 8 + i];
        ushort4 raw = *(const ushort4*)(stage + (size_t)m * 1024 + t * 4);
        acc.x += __uint_as_float((unsigned)raw.x << 16);
        acc.y += __uint_as_float((unsigned)raw.y << 16);
        acc.z += __uint_as_float((unsigned)raw.z << 16);
        acc.w += __uint_as_float((unsigned)raw.w << 16);
    }
    o4[t] = acc;
}

// ---------------- host ----------------

extern "C" void kernel_launch(void* const* d_in, const int* in_sizes, int n_in,
                              void* d_out, int out_size, void* d_ws, size_t ws_size,
                              hipStream_t stream) {
    (void)in_sizes; (void)n_in; (void)out_size;
    const float* X       = (const float*)d_in[0];
    const int*   labels  = (const int*)d_in[1];
    const float* centers = (const float*)d_in[2];
    const float* Wg  = (const float*)d_in[3];
    const float* Wu  = (const float*)d_in[4];
    const float* Wd  = (const float*)d_in[5];
    const float* uWg = (const float*)d_in[6];
    const float* uWu = (const float*)d_in[7];
    const float* uWd = (const float*)d_in[8];
    const float* sWg = (const float*)d_in[9];
    const float* sWu = (const float*)d_in[10];
    const float* sWd = (const float*)d_in[11];
    float* out = (float*)d_out;

    char* w = (char*)d_ws;
    auto alloc = [&](size_t n) { char* p = w; w += (n + 255) & ~(size_t)255; return p; };
    bf16* hid  = (bf16*)alloc((size_t)16384 * 1024 * 2);
    bf16* WgT  = (bf16*)alloc((size_t)8 * 2048 * 1024 * 2);
    bf16* WuT  = (bf16*)alloc((size_t)8 * 2048 * 1024 * 2);
    bf16* WdT  = (bf16*)alloc((size_t)8 * 2048 * 1024 * 2);
    bf16* uWgT = (bf16*)alloc((size_t)2048 * 1024 * 2);
    bf16* uWuT = (bf16*)alloc((size_t)2048 * 1024 * 2);
    bf16* uWdT = (bf16*)alloc((size_t)2048 * 1024 * 2);
    bf16* sWgT = (bf16*)alloc((size_t)2048 * 1024 * 2);
    bf16* sWuT = (bf16*)alloc((size_t)2048 * 1024 * 2);
    bf16* sWdT = (bf16*)alloc((size_t)2048 * 1024 * 2);
    float* P     = (float*)alloc((size_t)128 * 1024 * 4);
    float* invc  = (float*)alloc(256);
    int*   rmap  = (int*)alloc((size_t)32768 * 4);
    float* gsc   = (float*)alloc((size_t)32768 * 4);
    int*   cnt   = (int*)alloc((size_t)16384 * 4);
    int*   inv   = (int*)alloc((size_t)16384 * 8 * 4);

    // routed-output staging buffer (gsc-scaled bf16 rows, plain stores; no atomics).
    // Allocate ONLY if stage + >=8192 H rows both fit (else geometry collapses --
    // round-1 lesson: fragmented CR/EPG costs far more than atomics save).
    size_t used0 = (size_t)(w - (char*)d_ws);
    size_t rem0  = ws_size > used0 ? ws_size - used0 : 0;
    const size_t STAGE_BYTES = (size_t)32768 * 1024 * 2;   // 64 MiB bf16
    const size_t HMIN_BYTES  = (size_t)8192 * 2048 * 2;    // 32 MiB (EPG=2)
    bf16* stage = nullptr;
    if (rem0 >= STAGE_BYTES + HMIN_BYTES)
        stage = (bf16*)alloc(STAGE_BYTES);

    size_t used = (size_t)(w - (char*)d_ws);
    size_t hcap = ws_size > used ? ws_size - used : 0;
    bf16* H = (bf16*)w;
    long maxRows = (long)(hcap / ((size_t)2048 * 2));
    int CR = (int)(maxRows < 16384 ? maxRows : 16384);
    CR &= ~127;
    if (CR < 128) CR = 128;
    int EPG = 0;
    if (maxRows >= 32768) EPG = 8;
    else if (maxRows >= 16384) EPG = 4;
    else if (maxRows >= 8192)  EPG = 2;
    else if (maxRows >= 4096)  EPG = 1;

    const size_t WSTRIDE = (size_t)2048 * 1024;
    const int rmode = stage ? 2 : 3;

    cnorm_kernel<<<8, 256, 0, stream>>>(centers, invc);
    router_convert_kernel<<<16384, 256, 0, stream>>>(X, centers, invc, hid, P);
    softmax_kernel<<<128, 256, 0, stream>>>(P);
    zero_cnt_kernel<<<64, 256, 0, stream>>>(cnt);
    topk_kernel<<<128, 1024, 0, stream>>>(P, rmap, gsc, cnt, inv);
    transpose_cvt<<<dim3(64, 32, 16), 256, 0, stream>>>(Wg, WgT, 8, Wu, WuT, 1024, 2048);
    transpose_cvt<<<dim3(32, 64, 8), 256, 0, stream>>>(Wd, WdT, 8, nullptr, nullptr, 2048, 1024);
    transpose_cvt<<<dim3(64, 32, 2), 256, 0, stream>>>(uWg, uWgT, 1, sWg, sWgT, 1024, 2048);
    transpose_cvt<<<dim3(64, 32, 2), 256, 0, stream>>>(uWu, uWuT, 1, sWu, sWuT, 1024, 2048);
    transpose_cvt<<<dim3(32, 64, 2), 256, 0, stream>>>(uWd, uWdT, 1, sWd, sWdT, 2048, 1024);

    for (int m0 = 0; m0 < 16384; m0 += CR) {
        int rows = (16384 - m0 < CR) ? 16384 - m0 : CR;
        gateup_kernel<<<dim3(32, rows / 128, 1), 256, 0, stream>>>(
            hid, nullptr, sWgT, sWuT, H, rows, m0, labels, 0);
        down_kernel<<<dim3(8, rows / 128, 1), 256, 0, stream>>>(
            H, sWdT, out, nullptr, rows, m0, nullptr, nullptr, labels, 0);
    }
    for (int m0 = 0; m0 < 16384; m0 += CR) {
        int rows = (16384 - m0 < CR) ? 16384 - m0 : CR;
        gateup_kernel<<<dim3(32, rows / 128, 1), 256, 0, stream>>>(
            hid, nullptr, uWgT, uWuT, H, rows, m0, labels, 1);
        down_kernel<<<dim3(8, rows / 128, 1), 256, 0, stream>>>(
            H, uWdT, out, nullptr, rows, m0, nullptr, nullptr, labels, 1);
    }
    if (EPG > 0) {
        for (int g = 0; g < 8; g += EPG) {
            gateup_kernel<<<dim3(32, 32, EPG), 256, 0, stream>>>(
                hid, rmap + (size_t)g * 4096, WgT + (size_t)g * WSTRIDE,
                WuT + (size_t)g * WSTRIDE, H, 4096, 0, labels, 2);
            down_kernel<<<dim3(8, 32, EPG), 256, 0, stream>>>(
                H, WdT + (size_t)g * WSTRIDE, out,
                stage ? stage + (size_t)g * 4096 * 1024 : nullptr, 4096, 0,
                rmap + (size_t)g * 4096, gsc + (size_t)g * 4096, labels, rmode);
        }
    } else {
        for (int e = 0; e < 8; e++) {
            for (int m0 = 0; m0 < 4096; m0 += CR) {
                int rows = (4096 - m0 < CR) ? 4096 - m0 : CR;
                gateup_kernel<<<dim3(32, rows / 128, 1), 256, 0, stream>>>(
                    hid, rmap + (size_t)e * 4096 + m0, WgT + (size_t)e * WSTRIDE,
                    WuT + (size_t)e * WSTRIDE, H, rows, m0, labels, 2);
                down_kernel<<<dim3(8, rows / 128, 1), 256, 0, stream>>>(
                    H, WdT + (size_t)e * WSTRIDE, out,
                    stage ? stage + ((size_t)e * 4096 + m0) * 1024 : nullptr, rows, m0,
                    rmap + (size_t)e * 4096 + m0, gsc + (size_t)e * 4096 + m0, labels, rmode);
            }
        }
    }
    if (stage)
        combine_kernel<<<16384, 256, 0, stream>>>(stage, cnt, inv, labels, out);
}

// Round 4
// 1097.566 us; speedup vs baseline: 1.4933x; 1.1363x over previous
//
#include <hip/hip_runtime.h>
#include <stdint.h>

typedef __bf16 bf16;
typedef __attribute__((ext_vector_type(8))) __bf16 bf16x8;
typedef __attribute__((ext_vector_type(4))) float f32x4;

// async global->LDS, 16B per lane. LDS dest must be wave-uniform base + lane*16.
__device__ __forceinline__ void async_copy16(void* lds, const void* gp) {
    __builtin_amdgcn_global_load_lds(
        (__attribute__((address_space(1))) void*)(gp),
        (__attribute__((address_space(3))) void*)(lds), 16, 0, 0);
}

// LDS bank-conflict swizzle: logical chunk lq (16B) of row R lives at physical
// chunk (lq + (R>>1)) & 3.  Read-side address (in bf16 elements).
// Measured conflict-free (SQ_LDS_BANK_CONFLICT == 0 in rocprof, rounds 0-2).
__device__ __forceinline__ const bf16* lread(const bf16* base, int R, int lq) {
    return base + R * 32 + (((lq + (R >> 1)) & 3) << 3);
}
// Write side: lane t stages LDS offset t*16B = row (t>>2), phys chunk (t&3);
// the logical chunk it must fetch is ((t&3) - (t>>3)) & 3.

// XCD-aware block remap: xcd = flat%8 owns a contiguous slab of row-panels and
// iterates all N-tiles within a panel, so an A row-panel is fetched by ONE XCD's L2.
__device__ __forceinline__ void xcd_remap(int& bx, int& by, int& bz) {
    int gx = gridDim.x, gy = gridDim.y, gz = gridDim.z;
    int panels = gy * gz;
    if (panels & 7) { bx = blockIdx.x; by = blockIdx.y; bz = blockIdx.z; return; }
    int L = (blockIdx.z * gy + blockIdx.y) * gx + blockIdx.x;
    int X = L & 7, S = L >> 3;
    bx = S % gx;
    int P = S / gx;
    int byT = X * (panels >> 3) + P;
    bz = byT / gy;
    by = byT % gy;
}

// ---------------- router ----------------

__global__ __launch_bounds__(256) void cnorm_kernel(const float* __restrict__ centers,
                                                    float* __restrict__ invc) {
    int e = blockIdx.x, t = threadIdx.x;
    float4 v = ((const float4*)(centers + (size_t)e * 1024))[t];
    float ss = v.x * v.x + v.y * v.y + v.z * v.z + v.w * v.w;
    #pragma unroll
    for (int o = 32; o; o >>= 1) ss += __shfl_down(ss, o);
    __shared__ float red[4];
    if ((t & 63) == 0) red[t >> 6] = ss;
    __syncthreads();
    if (t == 0) invc[e] = 1.f / fmaxf(sqrtf(red[0] + red[1] + red[2] + red[3]), 1e-12f);
}

__global__ __launch_bounds__(256) void router_convert_kernel(
    const float* __restrict__ X, const float* __restrict__ centers,
    const float* __restrict__ invc, bf16* __restrict__ hid, float* __restrict__ P) {
    int tok = blockIdx.x, t = threadIdx.x;
    int b = tok >> 10, s = tok & 1023;
    float4 v = ((const float4*)(X + (size_t)tok * 1024))[t];
    union { bf16 h[4]; uint2 u; } cv;
    cv.h[0] = (bf16)v.x; cv.h[1] = (bf16)v.y; cv.h[2] = (bf16)v.z; cv.h[3] = (bf16)v.w;
    ((uint2*)(hid + (size_t)tok * 1024))[t] = cv.u;
    float ss = v.x * v.x + v.y * v.y + v.z * v.z + v.w * v.w;
    float dots[8];
    #pragma unroll
    for (int e = 0; e < 8; e++) {
        float4 c = ((const float4*)(centers + (size_t)e * 1024))[t];
        dots[e] = v.x * c.x + v.y * c.y + v.z * c.z + v.w * c.w;
    }
    #pragma unroll
    for (int o = 32; o; o >>= 1) {
        ss += __shfl_down(ss, o);
        #pragma unroll
        for (int e = 0; e < 8; e++) dots[e] += __shfl_down(dots[e], o);
    }
    __shared__ float red[4][9];
    if ((t & 63) == 0) {
        red[t >> 6][0] = ss;
        #pragma unroll
        for (int e = 0; e < 8; e++) red[t >> 6][1 + e] = dots[e];
    }
    __syncthreads();
    if (t < 8) {
        float S = red[0][0] + red[1][0] + red[2][0] + red[3][0];
        float rinv = 1.f / fmaxf(sqrtf(S), 1e-12f);
        float d = red[0][1 + t] + red[1][1 + t] + red[2][1 + t] + red[3][1 + t];
        P[((size_t)(b * 8 + t) << 10) + s] = d * rinv * invc[t];
    }
}

__global__ __launch_bounds__(256) void softmax_kernel(float* __restrict__ P) {
    int row = blockIdx.x, t = threadIdx.x;
    float4* p4 = (float4*)(P + ((size_t)row << 10));
    float4 v = p4[t];
    float mx = fmaxf(fmaxf(v.x, v.y), fmaxf(v.z, v.w));
    #pragma unroll
    for (int o = 32; o; o >>= 1) mx = fmaxf(mx, __shfl_down(mx, o));
    __shared__ float red[8];
    if ((t & 63) == 0) red[t >> 6] = mx;
    __syncthreads();
    float M = fmaxf(fmaxf(red[0], red[1]), fmaxf(red[2], red[3]));
    float e0 = expf(v.x - M), e1 = expf(v.y - M), e2 = expf(v.z - M), e3 = expf(v.w - M);
    float s = e0 + e1 + e2 + e3;
    #pragma unroll
    for (int o = 32; o; o >>= 1) s += __shfl_down(s, o);
    if ((t & 63) == 0) red[4 + (t >> 6)] = s;
    __syncthreads();
    float inv = 1.f / (red[4] + red[5] + red[6] + red[7]);
    p4[t] = make_float4(e0 * inv, e1 * inv, e2 * inv, e3 * inv);
}

__global__ __launch_bounds__(256) void zero_cnt_kernel(int* __restrict__ cnt) {
    cnt[blockIdx.x * 256 + threadIdx.x] = 0;
}

__global__ __launch_bounds__(1024) void topk_kernel(const float* __restrict__ P,
                                                    int* __restrict__ row_map,
                                                    float* __restrict__ gsc,
                                                    int* __restrict__ cnt,
                                                    int* __restrict__ inv) {
    int row = blockIdx.x, t = threadIdx.x;
    __shared__ unsigned long long keys[1024];
    float v = P[((size_t)row << 10) + t];
    unsigned u = __float_as_uint(v);
    u = (u & 0x80000000u) ? ~u : (u | 0x80000000u);
    keys[t] = ((unsigned long long)u << 32) | (unsigned)(~t);
    __syncthreads();
    for (int k = 2; k <= 1024; k <<= 1) {
        for (int j = k >> 1; j > 0; j >>= 1) {
            int ixj = t ^ j;
            if (ixj > t) {
                bool up = ((t & k) == 0);
                unsigned long long a = keys[t], b = keys[ixj];
                if ((a > b) == up) { keys[t] = b; keys[ixj] = a; }
            }
            __syncthreads();
        }
    }
    if (t >= 768) {
        int slot = t - 768;
        int s = (int)(~(unsigned)keys[t]) & 1023;
        int b = row >> 3, e = row & 7;
        int m = e * 4096 + b * 256 + slot;
        int tok = b * 1024 + s;
        row_map[m] = tok;
        gsc[m] = P[((size_t)row << 10) + s];
        // inverse map: token -> list of expert-slot indices (<=8, one per expert)
        int pos = atomicAdd(cnt + tok, 1);
        inv[tok * 8 + pos] = m;
    }
}

// ---------------- weight transpose-convert ----------------

__global__ __launch_bounds__(256) void transpose_cvt(
    const float* __restrict__ srcA, bf16* __restrict__ dstA, int batchA,
    const float* __restrict__ srcB, bf16* __restrict__ dstB, int R, int C) {
    int z = blockIdx.z;
    const float* src; bf16* dst;
    if (z < batchA) { src = srcA + (size_t)z * R * C; dst = dstA + (size_t)z * R * C; }
    else            { src = srcB + (size_t)(z - batchA) * R * C; dst = dstB + (size_t)(z - batchA) * R * C; }
    __shared__ float tile[32][33];
    int tx = threadIdx.x & 31, ty = threadIdx.x >> 5;
    int c0 = blockIdx.x * 32, r0 = blockIdx.y * 32;
    #pragma unroll
    for (int p = 0; p < 4; p++) {
        int r = p * 8 + ty;
        tile[r][tx] = src[(size_t)(r0 + r) * C + c0 + tx];
    }
    __syncthreads();
    #pragma unroll
    for (int p = 0; p < 4; p++) {
        int cl = p * 8 + ty;
        dst[(size_t)(c0 + cl) * R + r0 + tx] = (bf16)tile[tx][cl];
    }
}

// =============================================================================
// 256-tile GEMM engines, 8 waves (512 thr), BK=32, 2-deep double-buffered LDS
// with prefetch-before-compute.  ONE __syncthreads per K-step (its implicit
// vmcnt(0)/lgkmcnt(0) drain makes the schedule sound by construction):
//   iter k: STAGE into buf^1 (loads overlap the 32-MFMA compute below),
//           ds_read+MFMA on buf, __syncthreads, flip.
// Safety: only primitives verified in rounds 0-2 (global_load_lds, measured
// conflict-free swizzle, __syncthreads). 64KB static LDS.
// =============================================================================

// ---------------- fused gate+up GEMM: H = silu(X Wg) * (X Wu) ----------------
// tile 256(M) x 128(N of each g,u); K=1024. mode: 0=shared, 1=uncond, 2=routed

__global__ __launch_bounds__(512) void gateup_kernel(
    const bf16* __restrict__ X, const int* __restrict__ row_map,
    const bf16* __restrict__ WgT, const bf16* __restrict__ WuT,
    bf16* __restrict__ H, int Mz, int m_base, const int* __restrict__ labels, int mode) {
    int bx, by, z; xcd_remap(bx, by, z);
    if (mode == 1) { int b = (m_base + by * 256) >> 10; if (labels[b] != 1000) return; }
    if (mode == 2) { int b = (m_base + by * 256) >> 8;  if (labels[b] == 1000) return; }
    // per buffer (16384 bf16 = 32KB): A 256x32 | Bg 128x32 | Bu 128x32
    __shared__ bf16 lds[2 * 16384];
    const int t = threadIdx.x;
    const bf16* Wg_e = WgT + (size_t)z * 2048 * 1024;
    const bf16* Wu_e = WuT + (size_t)z * 2048 * 1024;
    bf16* H_e = H + (size_t)z * Mz * 2048;

    const int m0 = by * 256, n0 = bx * 128;
    const int r = t >> 2;                              // 0..127
    const int ce = (((t & 3) - (t >> 3)) & 3) * 8;     // swizzled source chunk
    int tok0, tok1;
    if (mode == 2) {
        const int* rm = row_map + (size_t)z * Mz;
        tok0 = rm[m0 + r]; tok1 = rm[m0 + 128 + r];
    } else { tok0 = m_base + m0 + r; tok1 = m_base + m0 + 128 + r; }
    const bf16* pa0 = X + (size_t)tok0 * 1024 + ce;
    const bf16* pa1 = X + (size_t)tok1 * 1024 + ce;
    const bf16* pg  = Wg_e + (size_t)(n0 + r) * 1024 + ce;
    const bf16* pu  = Wu_e + (size_t)(n0 + r) * 1024 + ce;

    const int l = t & 63, w = t >> 6;
    const int wm = w >> 2, wn = w & 3;                 // 2 x 4 waves
    const int lr = l & 15, lq = l >> 4;

    f32x4 accg[8][2] = {}, accu[8][2] = {};

    auto STAGE = [&](int s) {
        bf16* L = lds + s * 16384;
        async_copy16(L + t * 8, pa0);                  // A rows 0..127
        async_copy16(L + 4096 + t * 8, pa1);           // A rows 128..255
        async_copy16(L + 8192 + t * 8, pg);            // Bg rows 0..127
        async_copy16(L + 12288 + t * 8, pu);           // Bu rows 0..127
        pa0 += 32; pa1 += 32; pg += 32; pu += 32;
    };

    const int NT = 1024 / 32;
    STAGE(0);
    __syncthreads();
    int cur = 0;
    for (int kt = 0; kt < NT; ++kt) {
        if (kt + 1 < NT) STAGE(cur ^ 1);
        const bf16* As = lds + cur * 16384;
        const bf16* Bg = As + 8192;
        const bf16* Bu = As + 12288;
        bf16x8 a[8], bg[2], bu[2];
        #pragma unroll
        for (int mi = 0; mi < 8; mi++)
            a[mi] = *(const bf16x8*)lread(As, wm * 128 + mi * 16 + lr, lq);
        #pragma unroll
        for (int ni = 0; ni < 2; ni++) {
            bg[ni] = *(const bf16x8*)lread(Bg, wn * 32 + ni * 16 + lr, lq);
            bu[ni] = *(const bf16x8*)lread(Bu, wn * 32 + ni * 16 + lr, lq);
        }
        #pragma unroll
        for (int mi = 0; mi < 8; mi++)
            #pragma unroll
            for (int ni = 0; ni < 2; ni++) {
                accg[mi][ni] = __builtin_amdgcn_mfma_f32_16x16x32_bf16(a[mi], bg[ni], accg[mi][ni], 0, 0, 0);
                accu[mi][ni] = __builtin_amdgcn_mfma_f32_16x16x32_bf16(a[mi], bu[ni], accu[mi][ni], 0, 0, 0);
            }
        __syncthreads();
        cur ^= 1;
    }
    #pragma unroll
    for (int mi = 0; mi < 8; mi++)
        #pragma unroll
        for (int ni = 0; ni < 2; ni++)
            #pragma unroll
            for (int rr = 0; rr < 4; rr++) {
                int m = m0 + wm * 128 + mi * 16 + lq * 4 + rr;
                int n = n0 + wn * 32 + ni * 16 + lr;
                float g = accg[mi][ni][rr], uu = accu[mi][ni][rr];
                float h = g / (1.f + __expf(-g)) * uu;
                H_e[(size_t)m * 2048 + n] = (bf16)h;
            }
}

// ---------------- down GEMM: out = H WdT^T, K=2048, N=1024 ----------------
// tile 256(M) x 256(N). mode: 0=shared (=), 1=uncond (+=), 2=routed -> scaled
// bf16 store to stage, 3=routed legacy atomic scatter (workspace fallback)

__global__ __launch_bounds__(512) void down_kernel(
    const bf16* __restrict__ Hbase, const bf16* __restrict__ WdT,
    float* __restrict__ out, bf16* __restrict__ stage, int Mz, int m_base,
    const int* __restrict__ row_map, const float* __restrict__ gsc,
    const int* __restrict__ labels, int mode) {
    int bx, by, z; xcd_remap(bx, by, z);
    if (mode == 1) { int b = (m_base + by * 256) >> 10; if (labels[b] != 1000) return; }
    if (mode >= 2) { int b = (m_base + by * 256) >> 8;  if (labels[b] == 1000) return; }
    // per buffer (16384 bf16 = 32KB): A 256x32 | B 256x32
    __shared__ bf16 lds[2 * 16384];
    const int t = threadIdx.x;
    const bf16* A_e = Hbase + (size_t)z * Mz * 2048;
    const bf16* B_e = WdT + (size_t)z * 1024 * 2048;
    const int m0 = by * 256, n0 = bx * 256;
    const int r = t >> 2;
    const int ce = (((t & 3) - (t >> 3)) & 3) * 8;     // swizzled source chunk
    const bf16* pa0 = A_e + (size_t)(m0 + r) * 2048 + ce;
    const bf16* pa1 = A_e + (size_t)(m0 + 128 + r) * 2048 + ce;
    const bf16* pb0 = B_e + (size_t)(n0 + r) * 2048 + ce;
    const bf16* pb1 = B_e + (size_t)(n0 + 128 + r) * 2048 + ce;

    const int l = t & 63, w = t >> 6;
    const int wm = w >> 2, wn = w & 3;                 // 2 x 4 waves
    const int lr = l & 15, lq = l >> 4;

    f32x4 acc[8][4] = {};

    auto STAGE = [&](int s) {
        bf16* L = lds + s * 16384;
        async_copy16(L + t * 8, pa0);                  // A rows 0..127
        async_copy16(L + 4096 + t * 8, pa1);           // A rows 128..255
        async_copy16(L + 8192 + t * 8, pb0);           // B rows 0..127
        async_copy16(L + 12288 + t * 8, pb1);          // B rows 128..255
        pa0 += 32; pa1 += 32; pb0 += 32; pb1 += 32;
    };

    const int NT = 2048 / 32;
    STAGE(0);
    __syncthreads();
    int cur = 0;
    for (int kt = 0; kt < NT; ++kt) {
        if (kt + 1 < NT) STAGE(cur ^ 1);
        const bf16* As = lds + cur * 16384;
        const bf16* Bs = As + 8192;
        bf16x8 a[8], bb[4];
        #pragma unroll
        for (int mi = 0; mi < 8; mi++)
            a[mi] = *(const bf16x8*)lread(As, wm * 128 + mi * 16 + lr, lq);
        #pragma unroll
        for (int ni = 0; ni < 4; ni++)
            bb[ni] = *(const bf16x8*)lread(Bs, wn * 64 + ni * 16 + lr, lq);
        #pragma unroll
        for (int mi = 0; mi < 8; mi++)
            #pragma unroll
            for (int ni = 0; ni < 4; ni++)
                acc[mi][ni] = __builtin_amdgcn_mfma_f32_16x16x32_bf16(a[mi], bb[ni], acc[mi][ni], 0, 0, 0);
        __syncthreads();
        cur ^= 1;
    }
    float gs[8][4];
    if (mode >= 2) {
        #pragma unroll
        for (int mi = 0; mi < 8; mi++)
            #pragma unroll
            for (int rr = 0; rr < 4; rr++)
                gs[mi][rr] = gsc[(size_t)z * Mz + m0 + wm * 128 + mi * 16 + lq * 4 + rr];
    }
    #pragma unroll
    for (int mi = 0; mi < 8; mi++)
        #pragma unroll
        for (int ni = 0; ni < 4; ni++)
            #pragma unroll
            for (int rr = 0; rr < 4; rr++) {
                int m = m0 + wm * 128 + mi * 16 + lq * 4 + rr;
                int n = n0 + wn * 64 + ni * 16 + lr;
                float v = acc[mi][ni][rr];
                if (mode == 0) {
                    out[(size_t)(m_base + m) * 1024 + n] = v;
                } else if (mode == 1) {
                    out[(size_t)(m_base + m) * 1024 + n] += v;
                } else if (mode == 2) {
                    size_t em = (size_t)z * Mz + m;
                    stage[em * 1024 + n] = (bf16)(v * gs[mi][rr]);
                } else {
                    size_t em = (size_t)z * Mz + m;
                    int tok = row_map[em];
                    atomicAdd(out + (size_t)tok * 1024 + n, v * gs[mi][rr]);
                }
            }
}

// ---------------- combine: out[tok] += sum over experts that picked tok ----------------
// stage rows are already gsc-scaled (bf16); inverse map has <=8 entries per token.

__global__ __launch_bounds__(256) void combine_kernel(
    const bf16* __restrict__ stage, const int* __restrict__ cnt,
    const int* __restrict__ inv, const int* __restrict__ labels,
    float* __restrict__ out) {
    int tok = blockIdx.x;
    if (labels[tok >> 10] == 1000) return;   // routed output discarded for uncond batches
    int c = cnt[tok];
    if (c == 0) return;
    int t = threadIdx.x;
    float4* o4 = (float4*)(out + (size_t)tok * 1024);
    float4 acc = o4[t];
    for (int i = 0; i < c; i++) {
        int m = inv[tok * 8 + i];
        ushort4 raw = *(const ushort4*)(stage + (size_t)m * 1024 + t * 4);
        acc.x += __uint_as_float((unsigned)raw.x << 16);
        acc.y += __uint_as_float((unsigned)raw.y << 16);
        acc.z += __uint_as_float((unsigned)raw.z << 16);
        acc.w += __uint_as_float((unsigned)raw.w << 16);
    }
    o4[t] = acc;
}

// ---------------- host ----------------

extern "C" void kernel_launch(void* const* d_in, const int* in_sizes, int n_in,
                              void* d_out, int out_size, void* d_ws, size_t ws_size,
                              hipStream_t stream) {
    (void)in_sizes; (void)n_in; (void)out_size;
    const float* X       = (const float*)d_in[0];
    const int*   labels  = (const int*)d_in[1];
    const float* centers = (const float*)d_in[2];
    const float* Wg  = (const float*)d_in[3];
    const float* Wu  = (const float*)d_in[4];
    const float* Wd  = (const float*)d_in[5];
    const float* uWg = (const float*)d_in[6];
    const float* uWu = (const float*)d_in[7];
    const float* uWd = (const float*)d_in[8];
    const float* sWg = (const float*)d_in[9];
    const float* sWu = (const float*)d_in[10];
    const float* sWd = (const float*)d_in[11];
    float* out = (float*)d_out;

    char* w = (char*)d_ws;
    auto alloc = [&](size_t n) { char* p = w; w += (n + 255) & ~(size_t)255; return p; };
    bf16* hid  = (bf16*)alloc((size_t)16384 * 1024 * 2);
    bf16* WgT  = (bf16*)alloc((size_t)8 * 2048 * 1024 * 2);
    bf16* WuT  = (bf16*)alloc((size_t)8 * 2048 * 1024 * 2);
    bf16* WdT  = (bf16*)alloc((size_t)8 * 2048 * 1024 * 2);
    bf16* uWgT = (bf16*)alloc((size_t)2048 * 1024 * 2);
    bf16* uWuT = (bf16*)alloc((size_t)2048 * 1024 * 2);
    bf16* uWdT = (bf16*)alloc((size_t)2048 * 1024 * 2);
    bf16* sWgT = (bf16*)alloc((size_t)2048 * 1024 * 2);
    bf16* sWuT = (bf16*)alloc((size_t)2048 * 1024 * 2);
    bf16* sWdT = (bf16*)alloc((size_t)2048 * 1024 * 2);
    float* P     = (float*)alloc((size_t)128 * 1024 * 4);
    float* invc  = (float*)alloc(256);
    int*   rmap  = (int*)alloc((size_t)32768 * 4);
    float* gsc   = (float*)alloc((size_t)32768 * 4);
    int*   cnt   = (int*)alloc((size_t)16384 * 4);
    int*   inv   = (int*)alloc((size_t)16384 * 8 * 4);

    // routed-output staging buffer (gsc-scaled bf16 rows, plain stores; no atomics).
    // Allocate ONLY if stage + >=8192 H rows both fit (else geometry collapses --
    // round-1 lesson: fragmented CR/EPG costs far more than atomics save).
    size_t used0 = (size_t)(w - (char*)d_ws);
    size_t rem0  = ws_size > used0 ? ws_size - used0 : 0;
    const size_t STAGE_BYTES = (size_t)32768 * 1024 * 2;   // 64 MiB bf16
    const size_t HMIN_BYTES  = (size_t)8192 * 2048 * 2;    // 32 MiB (EPG=2)
    bf16* stage = nullptr;
    if (rem0 >= STAGE_BYTES + HMIN_BYTES)
        stage = (bf16*)alloc(STAGE_BYTES);

    size_t used = (size_t)(w - (char*)d_ws);
    size_t hcap = ws_size > used ? ws_size - used : 0;
    bf16* H = (bf16*)w;
    long maxRows = (long)(hcap / ((size_t)2048 * 2));
    int CR = (int)(maxRows < 16384 ? maxRows : 16384);
    CR &= ~255;
    if (CR < 256) CR = 256;
    int EPG = 0;
    if (maxRows >= 32768) EPG = 8;
    else if (maxRows >= 16384) EPG = 4;
    else if (maxRows >= 8192)  EPG = 2;
    else if (maxRows >= 4096)  EPG = 1;

    const size_t WSTRIDE = (size_t)2048 * 1024;
    const int rmode = stage ? 2 : 3;

    cnorm_kernel<<<8, 256, 0, stream>>>(centers, invc);
    router_convert_kernel<<<16384, 256, 0, stream>>>(X, centers, invc, hid, P);
    softmax_kernel<<<128, 256, 0, stream>>>(P);
    zero_cnt_kernel<<<64, 256, 0, stream>>>(cnt);
    topk_kernel<<<128, 1024, 0, stream>>>(P, rmap, gsc, cnt, inv);
    transpose_cvt<<<dim3(64, 32, 16), 256, 0, stream>>>(Wg, WgT, 8, Wu, WuT, 1024, 2048);
    transpose_cvt<<<dim3(32, 64, 8), 256, 0, stream>>>(Wd, WdT, 8, nullptr, nullptr, 2048, 1024);
    transpose_cvt<<<dim3(64, 32, 2), 256, 0, stream>>>(uWg, uWgT, 1, sWg, sWgT, 1024, 2048);
    transpose_cvt<<<dim3(64, 32, 2), 256, 0, stream>>>(uWu, uWuT, 1, sWu, sWuT, 1024, 2048);
    transpose_cvt<<<dim3(32, 64, 2), 256, 0, stream>>>(uWd, uWdT, 1, sWd, sWdT, 2048, 1024);

    for (int m0 = 0; m0 < 16384; m0 += CR) {
        int rows = (16384 - m0 < CR) ? 16384 - m0 : CR;
        gateup_kernel<<<dim3(16, rows / 256, 1), 512, 0, stream>>>(
            hid, nullptr, sWgT, sWuT, H, rows, m0, labels, 0);
        down_kernel<<<dim3(4, rows / 256, 1), 512, 0, stream>>>(
            H, sWdT, out, nullptr, rows, m0, nullptr, nullptr, labels, 0);
    }
    for (int m0 = 0; m0 < 16384; m0 += CR) {
        int rows = (16384 - m0 < CR) ? 16384 - m0 : CR;
        gateup_kernel<<<dim3(16, rows / 256, 1), 512, 0, stream>>>(
            hid, nullptr, uWgT, uWuT, H, rows, m0, labels, 1);
        down_kernel<<<dim3(4, rows / 256, 1), 512, 0, stream>>>(
            H, uWdT, out, nullptr, rows, m0, nullptr, nullptr, labels, 1);
    }
    if (EPG > 0) {
        for (int g = 0; g < 8; g += EPG) {
            gateup_kernel<<<dim3(16, 16, EPG), 512, 0, stream>>>(
                hid, rmap + (size_t)g * 4096, WgT + (size_t)g * WSTRIDE,
                WuT + (size_t)g * WSTRIDE, H, 4096, 0, labels, 2);
            down_kernel<<<dim3(4, 16, EPG), 512, 0, stream>>>(
                H, WdT + (size_t)g * WSTRIDE, out,
                stage ? stage + (size_t)g * 4096 * 1024 : nullptr, 4096, 0,
                rmap + (size_t)g * 4096, gsc + (size_t)g * 4096, labels, rmode);
        }
    } else {
        for (int e = 0; e < 8; e++) {
            for (int m0 = 0; m0 < 4096; m0 += CR) {
                int rows = (4096 - m0 < CR) ? 4096 - m0 : CR;
                gateup_kernel<<<dim3(16, rows / 256, 1), 512, 0, stream>>>(
                    hid, rmap + (size_t)e * 4096 + m0, WgT + (size_t)e * WSTRIDE,
                    WuT + (size_t)e * WSTRIDE, H, rows, m0, labels, 2);
                down_kernel<<<dim3(4, rows / 256, 1), 512, 0, stream>>>(
                    H, WdT + (size_t)e * WSTRIDE, out,
                    stage ? stage + ((size_t)e * 4096 + m0) * 1024 : nullptr, rows, m0,
                    rmap + (size_t)e * 4096 + m0, gsc + (size_t)e * 4096 + m0, labels, rmode);
            }
        }
    }
    if (stage)
        combine_kernel<<<16384, 256, 0, stream>>>(stage, cnt, inv, labels, out);
}

// Round 5
// 1061.731 us; speedup vs baseline: 1.5437x; 1.0338x over previous
//
#include <hip/hip_runtime.h>
#include <stdint.h>

typedef __bf16 bf16;
typedef __attribute__((ext_vector_type(8))) __bf16 bf16x8;
typedef __attribute__((ext_vector_type(4))) float f32x4;

// async global->LDS, 16B per lane. LDS dest must be wave-uniform base + lane*16.
__device__ __forceinline__ void async_copy16(void* lds, const void* gp) {
    __builtin_amdgcn_global_load_lds(
        (__attribute__((address_space(1))) void*)(gp),
        (__attribute__((address_space(3))) void*)(lds), 16, 0, 0);
}

// LDS bank-conflict swizzle: logical chunk lq (16B) of row R lives at physical
// chunk (lq + (R>>1)) & 3.  Read-side address (in bf16 elements).
// Measured conflict-free (SQ_LDS_BANK_CONFLICT == 0 in rounds 0-4).
__device__ __forceinline__ const bf16* lread(const bf16* base, int R, int lq) {
    return base + R * 32 + (((lq + (R >> 1)) & 3) << 3);
}
// Write side: lane t stages LDS offset t*16B = row (t>>2), phys chunk (t&3);
// the logical chunk it must fetch is ((t&3) - (t>>3)) & 3.

// XCD-aware block remap: xcd = flat%8 owns a contiguous slab of row-panels and
// iterates all N-tiles within a panel, so an A row-panel is fetched by ONE XCD's L2.
__device__ __forceinline__ void xcd_remap(int& bx, int& by, int& bz) {
    int gx = gridDim.x, gy = gridDim.y, gz = gridDim.z;
    int panels = gy * gz;
    if (panels & 7) { bx = blockIdx.x; by = blockIdx.y; bz = blockIdx.z; return; }
    int L = (blockIdx.z * gy + blockIdx.y) * gx + blockIdx.x;
    int X = L & 7, S = L >> 3;
    bx = S % gx;
    int P = S / gx;
    int byT = X * (panels >> 3) + P;
    bz = byT / gy;
    by = byT % gy;
}

// ---------------- router ----------------

__global__ __launch_bounds__(256) void cnorm_kernel(const float* __restrict__ centers,
                                                    float* __restrict__ invc) {
    int e = blockIdx.x, t = threadIdx.x;
    float4 v = ((const float4*)(centers + (size_t)e * 1024))[t];
    float ss = v.x * v.x + v.y * v.y + v.z * v.z + v.w * v.w;
    #pragma unroll
    for (int o = 32; o; o >>= 1) ss += __shfl_down(ss, o);
    __shared__ float red[4];
    if ((t & 63) == 0) red[t >> 6] = ss;
    __syncthreads();
    if (t == 0) invc[e] = 1.f / fmaxf(sqrtf(red[0] + red[1] + red[2] + red[3]), 1e-12f);
}

__global__ __launch_bounds__(256) void router_convert_kernel(
    const float* __restrict__ X, const float* __restrict__ centers,
    const float* __restrict__ invc, bf16* __restrict__ hid, float* __restrict__ P) {
    int tok = blockIdx.x, t = threadIdx.x;
    int b = tok >> 10, s = tok & 1023;
    float4 v = ((const float4*)(X + (size_t)tok * 1024))[t];
    union { bf16 h[4]; uint2 u; } cv;
    cv.h[0] = (bf16)v.x; cv.h[1] = (bf16)v.y; cv.h[2] = (bf16)v.z; cv.h[3] = (bf16)v.w;
    ((uint2*)(hid + (size_t)tok * 1024))[t] = cv.u;
    float ss = v.x * v.x + v.y * v.y + v.z * v.z + v.w * v.w;
    float dots[8];
    #pragma unroll
    for (int e = 0; e < 8; e++) {
        float4 c = ((const float4*)(centers + (size_t)e * 1024))[t];
        dots[e] = v.x * c.x + v.y * c.y + v.z * c.z + v.w * c.w;
    }
    #pragma unroll
    for (int o = 32; o; o >>= 1) {
        ss += __shfl_down(ss, o);
        #pragma unroll
        for (int e = 0; e < 8; e++) dots[e] += __shfl_down(dots[e], o);
    }
    __shared__ float red[4][9];
    if ((t & 63) == 0) {
        red[t >> 6][0] = ss;
        #pragma unroll
        for (int e = 0; e < 8; e++) red[t >> 6][1 + e] = dots[e];
    }
    __syncthreads();
    if (t < 8) {
        float S = red[0][0] + red[1][0] + red[2][0] + red[3][0];
        float rinv = 1.f / fmaxf(sqrtf(S), 1e-12f);
        float d = red[0][1 + t] + red[1][1 + t] + red[2][1 + t] + red[3][1 + t];
        P[((size_t)(b * 8 + t) << 10) + s] = d * rinv * invc[t];
    }
}

__global__ __launch_bounds__(256) void softmax_kernel(float* __restrict__ P) {
    int row = blockIdx.x, t = threadIdx.x;
    float4* p4 = (float4*)(P + ((size_t)row << 10));
    float4 v = p4[t];
    float mx = fmaxf(fmaxf(v.x, v.y), fmaxf(v.z, v.w));
    #pragma unroll
    for (int o = 32; o; o >>= 1) mx = fmaxf(mx, __shfl_down(mx, o));
    __shared__ float red[8];
    if ((t & 63) == 0) red[t >> 6] = mx;
    __syncthreads();
    float M = fmaxf(fmaxf(red[0], red[1]), fmaxf(red[2], red[3]));
    float e0 = expf(v.x - M), e1 = expf(v.y - M), e2 = expf(v.z - M), e3 = expf(v.w - M);
    float s = e0 + e1 + e2 + e3;
    #pragma unroll
    for (int o = 32; o; o >>= 1) s += __shfl_down(s, o);
    if ((t & 63) == 0) red[4 + (t >> 6)] = s;
    __syncthreads();
    float inv = 1.f / (red[4] + red[5] + red[6] + red[7]);
    p4[t] = make_float4(e0 * inv, e1 * inv, e2 * inv, e3 * inv);
}

__global__ __launch_bounds__(256) void zero_cnt_kernel(int* __restrict__ cnt) {
    cnt[blockIdx.x * 256 + threadIdx.x] = 0;
}

__global__ __launch_bounds__(1024) void topk_kernel(const float* __restrict__ P,
                                                    int* __restrict__ row_map,
                                                    float* __restrict__ gsc,
                                                    int* __restrict__ cnt,
                                                    int* __restrict__ inv) {
    int row = blockIdx.x, t = threadIdx.x;
    __shared__ unsigned long long keys[1024];
    float v = P[((size_t)row << 10) + t];
    unsigned u = __float_as_uint(v);
    u = (u & 0x80000000u) ? ~u : (u | 0x80000000u);
    keys[t] = ((unsigned long long)u << 32) | (unsigned)(~t);
    __syncthreads();
    for (int k = 2; k <= 1024; k <<= 1) {
        for (int j = k >> 1; j > 0; j >>= 1) {
            int ixj = t ^ j;
            if (ixj > t) {
                bool up = ((t & k) == 0);
                unsigned long long a = keys[t], b = keys[ixj];
                if ((a > b) == up) { keys[t] = b; keys[ixj] = a; }
            }
            __syncthreads();
        }
    }
    if (t >= 768) {
        int slot = t - 768;
        int s = (int)(~(unsigned)keys[t]) & 1023;
        int b = row >> 3, e = row & 7;
        int m = e * 4096 + b * 256 + slot;
        int tok = b * 1024 + s;
        row_map[m] = tok;
        gsc[m] = P[((size_t)row << 10) + s];
        // inverse map: token -> list of expert-slot indices (<=8, one per expert)
        int pos = atomicAdd(cnt + tok, 1);
        inv[tok * 8 + pos] = m;
    }
}

// ---------------- weight transpose-convert ----------------

__global__ __launch_bounds__(256) void transpose_cvt(
    const float* __restrict__ srcA, bf16* __restrict__ dstA, int batchA,
    const float* __restrict__ srcB, bf16* __restrict__ dstB, int R, int C) {
    int z = blockIdx.z;
    const float* src; bf16* dst;
    if (z < batchA) { src = srcA + (size_t)z * R * C; dst = dstA + (size_t)z * R * C; }
    else            { src = srcB + (size_t)(z - batchA) * R * C; dst = dstB + (size_t)(z - batchA) * R * C; }
    __shared__ float tile[32][33];
    int tx = threadIdx.x & 31, ty = threadIdx.x >> 5;
    int c0 = blockIdx.x * 32, r0 = blockIdx.y * 32;
    #pragma unroll
    for (int p = 0; p < 4; p++) {
        int r = p * 8 + ty;
        tile[r][tx] = src[(size_t)(r0 + r) * C + c0 + tx];
    }
    __syncthreads();
    #pragma unroll
    for (int p = 0; p < 4; p++) {
        int cl = p * 8 + ty;
        dst[(size_t)(c0 + cl) * R + r0 + tx] = (bf16)tile[tx][cl];
    }
}

// =============================================================================
// 256-tile GEMM engines, 8 waves (512 thr), BK=64, 2-deep double-buffered LDS.
// BK=64 is realized as TWO concatenated BK=32 sub-buffers, each with the exact
// verified round-4 layout/swizzle/STAGE addressing.  Per K-iter: stage both
// halves of the next tile, compute both halves of the current (64 MFMA/wave),
// ONE __syncthreads (its implicit vmcnt(0)/lgkmcnt(0) drain keeps the schedule
// sound by construction).  128KB static LDS, 1 block/CU (measured occupancy
// was already ~1 block at 64KB, so nothing is lost).
// =============================================================================

// ---------------- fused gate+up GEMM: H = silu(X Wg) * (X Wu) ----------------
// tile 256(M) x 128(N of each g,u); K=1024. mode: 0=shared, 1=uncond, 2=routed

__global__ __launch_bounds__(512) void gateup_kernel(
    const bf16* __restrict__ X, const int* __restrict__ row_map,
    const bf16* __restrict__ WgT, const bf16* __restrict__ WuT,
    bf16* __restrict__ H, int Mz, int m_base, const int* __restrict__ labels, int mode) {
    int bx, by, z; xcd_remap(bx, by, z);
    if (mode == 1) { int b = (m_base + by * 256) >> 10; if (labels[b] != 1000) return; }
    if (mode == 2) { int b = (m_base + by * 256) >> 8;  if (labels[b] == 1000) return; }
    // buffer = 2 sub-buffers; each sub (16384 bf16 = 32KB): A 256x32 | Bg 128x32 | Bu 128x32
    __shared__ bf16 lds[2 * 32768];
    const int t = threadIdx.x;
    const bf16* Wg_e = WgT + (size_t)z * 2048 * 1024;
    const bf16* Wu_e = WuT + (size_t)z * 2048 * 1024;
    bf16* H_e = H + (size_t)z * Mz * 2048;

    const int m0 = by * 256, n0 = bx * 128;
    const int r = t >> 2;                              // 0..127
    const int ce = (((t & 3) - (t >> 3)) & 3) * 8;     // swizzled source chunk
    int tok0, tok1;
    if (mode == 2) {
        const int* rm = row_map + (size_t)z * Mz;
        tok0 = rm[m0 + r]; tok1 = rm[m0 + 128 + r];
    } else { tok0 = m_base + m0 + r; tok1 = m_base + m0 + 128 + r; }
    const bf16* pa0 = X + (size_t)tok0 * 1024 + ce;
    const bf16* pa1 = X + (size_t)tok1 * 1024 + ce;
    const bf16* pg  = Wg_e + (size_t)(n0 + r) * 1024 + ce;
    const bf16* pu  = Wu_e + (size_t)(n0 + r) * 1024 + ce;

    const int l = t & 63, w = t >> 6;
    const int wm = w >> 2, wn = w & 3;                 // 2 x 4 waves
    const int lr = l & 15, lq = l >> 4;

    f32x4 accg[8][2] = {}, accu[8][2] = {};

    auto STAGE = [&](int s) {
        bf16* L = lds + s * 32768;
        #pragma unroll
        for (int kk = 0; kk < 2; kk++) {
            bf16* S = L + kk * 16384;
            const int o = kk * 32;
            async_copy16(S + t * 8,         pa0 + o);   // A rows 0..127
            async_copy16(S + 4096 + t * 8,  pa1 + o);   // A rows 128..255
            async_copy16(S + 8192 + t * 8,  pg + o);    // Bg rows 0..127
            async_copy16(S + 12288 + t * 8, pu + o);    // Bu rows 0..127
        }
        pa0 += 64; pa1 += 64; pg += 64; pu += 64;
    };

    const int NT = 1024 / 64;
    STAGE(0);
    __syncthreads();
    int cur = 0;
    for (int kt = 0; kt < NT; ++kt) {
        if (kt + 1 < NT) STAGE(cur ^ 1);
        #pragma unroll
        for (int kk = 0; kk < 2; kk++) {
            const bf16* As = lds + cur * 32768 + kk * 16384;
            const bf16* Bg = As + 8192;
            const bf16* Bu = As + 12288;
            bf16x8 a[8], bg[2], bu[2];
            #pragma unroll
            for (int mi = 0; mi < 8; mi++)
                a[mi] = *(const bf16x8*)lread(As, wm * 128 + mi * 16 + lr, lq);
            #pragma unroll
            for (int ni = 0; ni < 2; ni++) {
                bg[ni] = *(const bf16x8*)lread(Bg, wn * 32 + ni * 16 + lr, lq);
                bu[ni] = *(const bf16x8*)lread(Bu, wn * 32 + ni * 16 + lr, lq);
            }
            #pragma unroll
            for (int mi = 0; mi < 8; mi++)
                #pragma unroll
                for (int ni = 0; ni < 2; ni++) {
                    accg[mi][ni] = __builtin_amdgcn_mfma_f32_16x16x32_bf16(a[mi], bg[ni], accg[mi][ni], 0, 0, 0);
                    accu[mi][ni] = __builtin_amdgcn_mfma_f32_16x16x32_bf16(a[mi], bu[ni], accu[mi][ni], 0, 0, 0);
                }
        }
        __syncthreads();
        cur ^= 1;
    }
    #pragma unroll
    for (int mi = 0; mi < 8; mi++)
        #pragma unroll
        for (int ni = 0; ni < 2; ni++)
            #pragma unroll
            for (int rr = 0; rr < 4; rr++) {
                int m = m0 + wm * 128 + mi * 16 + lq * 4 + rr;
                int n = n0 + wn * 32 + ni * 16 + lr;
                float g = accg[mi][ni][rr], uu = accu[mi][ni][rr];
                float h = g / (1.f + __expf(-g)) * uu;
                H_e[(size_t)m * 2048 + n] = (bf16)h;
            }
}

// ---------------- down GEMM: out = H WdT^T, K=2048, N=1024 ----------------
// tile 256(M) x 256(N). mode: 0=shared (=), 1=uncond (+=), 2=routed -> scaled
// bf16 store to stage, 3=routed legacy atomic scatter (workspace fallback)

__global__ __launch_bounds__(512) void down_kernel(
    const bf16* __restrict__ Hbase, const bf16* __restrict__ WdT,
    float* __restrict__ out, bf16* __restrict__ stage, int Mz, int m_base,
    const int* __restrict__ row_map, const float* __restrict__ gsc,
    const int* __restrict__ labels, int mode) {
    int bx, by, z; xcd_remap(bx, by, z);
    if (mode == 1) { int b = (m_base + by * 256) >> 10; if (labels[b] != 1000) return; }
    if (mode >= 2) { int b = (m_base + by * 256) >> 8;  if (labels[b] == 1000) return; }
    // buffer = 2 sub-buffers; each sub (16384 bf16 = 32KB): A 256x32 | B 256x32
    __shared__ bf16 lds[2 * 32768];
    const int t = threadIdx.x;
    const bf16* A_e = Hbase + (size_t)z * Mz * 2048;
    const bf16* B_e = WdT + (size_t)z * 1024 * 2048;
    const int m0 = by * 256, n0 = bx * 256;
    const int r = t >> 2;
    const int ce = (((t & 3) - (t >> 3)) & 3) * 8;     // swizzled source chunk
    const bf16* pa0 = A_e + (size_t)(m0 + r) * 2048 + ce;
    const bf16* pa1 = A_e + (size_t)(m0 + 128 + r) * 2048 + ce;
    const bf16* pb0 = B_e + (size_t)(n0 + r) * 2048 + ce;
    const bf16* pb1 = B_e + (size_t)(n0 + 128 + r) * 2048 + ce;

    const int l = t & 63, w = t >> 6;
    const int wm = w >> 2, wn = w & 3;                 // 2 x 4 waves
    const int lr = l & 15, lq = l >> 4;

    f32x4 acc[8][4] = {};

    auto STAGE = [&](int s) {
        bf16* L = lds + s * 32768;
        #pragma unroll
        for (int kk = 0; kk < 2; kk++) {
            bf16* S = L + kk * 16384;
            const int o = kk * 32;
            async_copy16(S + t * 8,         pa0 + o);   // A rows 0..127
            async_copy16(S + 4096 + t * 8,  pa1 + o);   // A rows 128..255
            async_copy16(S + 8192 + t * 8,  pb0 + o);   // B rows 0..127
            async_copy16(S + 12288 + t * 8, pb1 + o);   // B rows 128..255
        }
        pa0 += 64; pa1 += 64; pb0 += 64; pb1 += 64;
    };

    const int NT = 2048 / 64;
    STAGE(0);
    __syncthreads();
    int cur = 0;
    for (int kt = 0; kt < NT; ++kt) {
        if (kt + 1 < NT) STAGE(cur ^ 1);
        #pragma unroll
        for (int kk = 0; kk < 2; kk++) {
            const bf16* As = lds + cur * 32768 + kk * 16384;
            const bf16* Bs = As + 8192;
            bf16x8 a[8], bb[4];
            #pragma unroll
            for (int mi = 0; mi < 8; mi++)
                a[mi] = *(const bf16x8*)lread(As, wm * 128 + mi * 16 + lr, lq);
            #pragma unroll
            for (int ni = 0; ni < 4; ni++)
                bb[ni] = *(const bf16x8*)lread(Bs, wn * 64 + ni * 16 + lr, lq);
            #pragma unroll
            for (int mi = 0; mi < 8; mi++)
                #pragma unroll
                for (int ni = 0; ni < 4; ni++)
                    acc[mi][ni] = __builtin_amdgcn_mfma_f32_16x16x32_bf16(a[mi], bb[ni], acc[mi][ni], 0, 0, 0);
        }
        __syncthreads();
        cur ^= 1;
    }
    float gs[8][4];
    if (mode >= 2) {
        #pragma unroll
        for (int mi = 0; mi < 8; mi++)
            #pragma unroll
            for (int rr = 0; rr < 4; rr++)
                gs[mi][rr] = gsc[(size_t)z * Mz + m0 + wm * 128 + mi * 16 + lq * 4 + rr];
    }
    #pragma unroll
    for (int mi = 0; mi < 8; mi++)
        #pragma unroll
        for (int ni = 0; ni < 4; ni++)
            #pragma unroll
            for (int rr = 0; rr < 4; rr++) {
                int m = m0 + wm * 128 + mi * 16 + lq * 4 + rr;
                int n = n0 + wn * 64 + ni * 16 + lr;
                float v = acc[mi][ni][rr];
                if (mode == 0) {
                    out[(size_t)(m_base + m) * 1024 + n] = v;
                } else if (mode == 1) {
                    out[(size_t)(m_base + m) * 1024 + n] += v;
                } else if (mode == 2) {
                    size_t em = (size_t)z * Mz + m;
                    stage[em * 1024 + n] = (bf16)(v * gs[mi][rr]);
                } else {
                    size_t em = (size_t)z * Mz + m;
                    int tok = row_map[em];
                    atomicAdd(out + (size_t)tok * 1024 + n, v * gs[mi][rr]);
                }
            }
}

// ---------------- combine: out[tok] += sum over experts that picked tok ----------------
// stage rows are already gsc-scaled (bf16); inverse map has <=8 entries per token.

__global__ __launch_bounds__(256) void combine_kernel(
    const bf16* __restrict__ stage, const int* __restrict__ cnt,
    const int* __restrict__ inv, const int* __restrict__ labels,
    float* __restrict__ out) {
    int tok = blockIdx.x;
    if (labels[tok >> 10] == 1000) return;   // routed output discarded for uncond batches
    int c = cnt[tok];
    if (c == 0) return;
    int t = threadIdx.x;
    float4* o4 = (float4*)(out + (size_t)tok * 1024);
    float4 acc = o4[t];
    for (int i = 0; i < c; i++) {
        int m = inv[tok * 8 + i];
        ushort4 raw = *(const ushort4*)(stage + (size_t)m * 1024 + t * 4);
        acc.x += __uint_as_float((unsigned)raw.x << 16);
        acc.y += __uint_as_float((unsigned)raw.y << 16);
        acc.z += __uint_as_float((unsigned)raw.z << 16);
        acc.w += __uint_as_float((unsigned)raw.w << 16);
    }
    o4[t] = acc;
}

// ---------------- host ----------------

extern "C" void kernel_launch(void* const* d_in, const int* in_sizes, int n_in,
                              void* d_out, int out_size, void* d_ws, size_t ws_size,
                              hipStream_t stream) {
    (void)in_sizes; (void)n_in; (void)out_size;
    const float* X       = (const float*)d_in[0];
    const int*   labels  = (const int*)d_in[1];
    const float* centers = (const float*)d_in[2];
    const float* Wg  = (const float*)d_in[3];
    const float* Wu  = (const float*)d_in[4];
    const float* Wd  = (const float*)d_in[5];
    const float* uWg = (const float*)d_in[6];
    const float* uWu = (const float*)d_in[7];
    const float* uWd = (const float*)d_in[8];
    const float* sWg = (const float*)d_in[9];
    const float* sWu = (const float*)d_in[10];
    const float* sWd = (const float*)d_in[11];
    float* out = (float*)d_out;

    char* w = (char*)d_ws;
    auto alloc = [&](size_t n) { char* p = w; w += (n + 255) & ~(size_t)255; return p; };
    bf16* hid  = (bf16*)alloc((size_t)16384 * 1024 * 2);
    bf16* WgT  = (bf16*)alloc((size_t)8 * 2048 * 1024 * 2);
    bf16* WuT  = (bf16*)alloc((size_t)8 * 2048 * 1024 * 2);
    bf16* WdT  = (bf16*)alloc((size_t)8 * 2048 * 1024 * 2);
    bf16* uWgT = (bf16*)alloc((size_t)2048 * 1024 * 2);
    bf16* uWuT = (bf16*)alloc((size_t)2048 * 1024 * 2);
    bf16* uWdT = (bf16*)alloc((size_t)2048 * 1024 * 2);
    bf16* sWgT = (bf16*)alloc((size_t)2048 * 1024 * 2);
    bf16* sWuT = (bf16*)alloc((size_t)2048 * 1024 * 2);
    bf16* sWdT = (bf16*)alloc((size_t)2048 * 1024 * 2);
    float* P     = (float*)alloc((size_t)128 * 1024 * 4);
    float* invc  = (float*)alloc(256);
    int*   rmap  = (int*)alloc((size_t)32768 * 4);
    float* gsc   = (float*)alloc((size_t)32768 * 4);
    int*   cnt   = (int*)alloc((size_t)16384 * 4);
    int*   inv   = (int*)alloc((size_t)16384 * 8 * 4);

    // routed-output staging buffer (gsc-scaled bf16 rows, plain stores; no atomics).
    // Allocate ONLY if stage + >=8192 H rows both fit (else geometry collapses --
    // round-1 lesson: fragmented CR/EPG costs far more than atomics save).
    size_t used0 = (size_t)(w - (char*)d_ws);
    size_t rem0  = ws_size > used0 ? ws_size - used0 : 0;
    const size_t STAGE_BYTES = (size_t)32768 * 1024 * 2;   // 64 MiB bf16
    const size_t HMIN_BYTES  = (size_t)8192 * 2048 * 2;    // 32 MiB (EPG=2)
    bf16* stage = nullptr;
    if (rem0 >= STAGE_BYTES + HMIN_BYTES)
        stage = (bf16*)alloc(STAGE_BYTES);

    size_t used = (size_t)(w - (char*)d_ws);
    size_t hcap = ws_size > used ? ws_size - used : 0;
    bf16* H = (bf16*)w;
    long maxRows = (long)(hcap / ((size_t)2048 * 2));
    int CR = (int)(maxRows < 16384 ? maxRows : 16384);
    CR &= ~255;
    if (CR < 256) CR = 256;
    int EPG = 0;
    if (maxRows >= 32768) EPG = 8;
    else if (maxRows >= 16384) EPG = 4;
    else if (maxRows >= 8192)  EPG = 2;
    else if (maxRows >= 4096)  EPG = 1;

    const size_t WSTRIDE = (size_t)2048 * 1024;
    const int rmode = stage ? 2 : 3;

    cnorm_kernel<<<8, 256, 0, stream>>>(centers, invc);
    router_convert_kernel<<<16384, 256, 0, stream>>>(X, centers, invc, hid, P);
    softmax_kernel<<<128, 256, 0, stream>>>(P);
    zero_cnt_kernel<<<64, 256, 0, stream>>>(cnt);
    topk_kernel<<<128, 1024, 0, stream>>>(P, rmap, gsc, cnt, inv);
    transpose_cvt<<<dim3(64, 32, 16), 256, 0, stream>>>(Wg, WgT, 8, Wu, WuT, 1024, 2048);
    transpose_cvt<<<dim3(32, 64, 8), 256, 0, stream>>>(Wd, WdT, 8, nullptr, nullptr, 2048, 1024);
    transpose_cvt<<<dim3(64, 32, 2), 256, 0, stream>>>(uWg, uWgT, 1, sWg, sWgT, 1024, 2048);
    transpose_cvt<<<dim3(64, 32, 2), 256, 0, stream>>>(uWu, uWuT, 1, sWu, sWuT, 1024, 2048);
    transpose_cvt<<<dim3(32, 64, 2), 256, 0, stream>>>(uWd, uWdT, 1, sWd, sWdT, 2048, 1024);

    for (int m0 = 0; m0 < 16384; m0 += CR) {
        int rows = (16384 - m0 < CR) ? 16384 - m0 : CR;
        gateup_kernel<<<dim3(16, rows / 256, 1), 512, 0, stream>>>(
            hid, nullptr, sWgT, sWuT, H, rows, m0, labels, 0);
        down_kernel<<<dim3(4, rows / 256, 1), 512, 0, stream>>>(
            H, sWdT, out, nullptr, rows, m0, nullptr, nullptr, labels, 0);
    }
    for (int m0 = 0; m0 < 16384; m0 += CR) {
        int rows = (16384 - m0 < CR) ? 16384 - m0 : CR;
        gateup_kernel<<<dim3(16, rows / 256, 1), 512, 0, stream>>>(
            hid, nullptr, uWgT, uWuT, H, rows, m0, labels, 1);
        down_kernel<<<dim3(4, rows / 256, 1), 512, 0, stream>>>(
            H, uWdT, out, nullptr, rows, m0, nullptr, nullptr, labels, 1);
    }
    if (EPG > 0) {
        for (int g = 0; g < 8; g += EPG) {
            gateup_kernel<<<dim3(16, 16, EPG), 512, 0, stream>>>(
                hid, rmap + (size_t)g * 4096, WgT + (size_t)g * WSTRIDE,
                WuT + (size_t)g * WSTRIDE, H, 4096, 0, labels, 2);
            down_kernel<<<dim3(4, 16, EPG), 512, 0, stream>>>(
                H, WdT + (size_t)g * WSTRIDE, out,
                stage ? stage + (size_t)g * 4096 * 1024 : nullptr, 4096, 0,
                rmap + (size_t)g * 4096, gsc + (size_t)g * 4096, labels, rmode);
        }
    } else {
        for (int e = 0; e < 8; e++) {
            for (int m0 = 0; m0 < 4096; m0 += CR) {
                int rows = (4096 - m0 < CR) ? 4096 - m0 : CR;
                gateup_kernel<<<dim3(16, rows / 256, 1), 512, 0, stream>>>(
                    hid, rmap + (size_t)e * 4096 + m0, WgT + (size_t)e * WSTRIDE,
                    WuT + (size_t)e * WSTRIDE, H, rows, m0, labels, 2);
                down_kernel<<<dim3(4, rows / 256, 1), 512, 0, stream>>>(
                    H, WdT + (size_t)e * WSTRIDE, out,
                    stage ? stage + ((size_t)e * 4096 + m0) * 1024 : nullptr, rows, m0,
                    rmap + (size_t)e * 4096 + m0, gsc + (size_t)e * 4096 + m0, labels, rmode);
            }
        }
    }
    if (stage)
        combine_kernel<<<16384, 256, 0, stream>>>(stage, cnt, inv, labels, out);
}